// Round 1
// baseline (640.131 us; speedup 1.0000x reference)
//
#include <hip/hip_runtime.h>
#include <cmath>

typedef unsigned short u16;
typedef unsigned int u32;
typedef __bf16 bf16x8 __attribute__((ext_vector_type(8)));
typedef float f32x4 __attribute__((ext_vector_type(4)));

#define SEQ 2048
#define EMB 1024
#define NHEAD 16
#define HDIM 64
#define FFDIM 4096
#define NBATCH 2

__device__ __forceinline__ u16 f2bf(float f) {
  u32 u = __float_as_uint(f);
  u32 r = u + 0x7fffu + ((u >> 16) & 1u);
  return (u16)(r >> 16);
}

__device__ __forceinline__ float geluf(float x) {
  return 0.5f * x * (1.0f + erff(x * 0.70710678118654752f));
}

// ---------------- weight transpose + fp32->bf16 ----------------
// W [K,N] fp32 -> WT [N,K] bf16
__global__ __launch_bounds__(256)
void wtrans_kernel(const float* __restrict__ W, u16* __restrict__ WT, int K, int N) {
  __shared__ float tile[32][33];
  int tx = threadIdx.x & 31, ty = threadIdx.x >> 5;
  int n0 = blockIdx.x * 32, k0 = blockIdx.y * 32;
#pragma unroll
  for (int i = 0; i < 32; i += 8)
    tile[ty + i][tx] = W[(size_t)(k0 + ty + i) * N + (n0 + tx)];
  __syncthreads();
#pragma unroll
  for (int i = 0; i < 32; i += 8)
    WT[(size_t)(n0 + ty + i) * K + (k0 + tx)] = f2bf(tile[tx][ty + i]);
}

// ---------------- layernorm (fp32 in, bf16 out + optional fp32 out) -----------
__global__ __launch_bounds__(256)
void ln_kernel(const float* __restrict__ in, const float* __restrict__ gamma,
               const float* __restrict__ beta, u16* __restrict__ outb,
               float* __restrict__ outf) {
  int row = blockIdx.x, tid = threadIdx.x;
  size_t base = (size_t)row * EMB + tid * 4;
  float4 v = *(const float4*)(in + base);
  float s = v.x + v.y + v.z + v.w;
  float q = v.x * v.x + v.y * v.y + v.z * v.z + v.w * v.w;
#pragma unroll
  for (int off = 1; off < 64; off <<= 1) {
    s += __shfl_xor(s, off);
    q += __shfl_xor(q, off);
  }
  __shared__ float ss[4], sq[4];
  int w = tid >> 6, lane = tid & 63;
  if (lane == 0) { ss[w] = s; sq[w] = q; }
  __syncthreads();
  float ts = ss[0] + ss[1] + ss[2] + ss[3];
  float tq = sq[0] + sq[1] + sq[2] + sq[3];
  float mean = ts * (1.0f / EMB);
  float var = tq * (1.0f / EMB) - mean * mean;
  float rstd = rsqrtf(var + 1e-5f);
  float4 g4 = *(const float4*)(gamma + tid * 4);
  float4 b4 = *(const float4*)(beta + tid * 4);
  float y0 = (v.x - mean) * rstd * g4.x + b4.x;
  float y1 = (v.y - mean) * rstd * g4.y + b4.y;
  float y2 = (v.z - mean) * rstd * g4.z + b4.z;
  float y3 = (v.w - mean) * rstd * g4.w + b4.w;
  ushort4 ob;
  ob.x = f2bf(y0); ob.y = f2bf(y1); ob.z = f2bf(y2); ob.w = f2bf(y3);
  *(ushort4*)(outb + base) = ob;
  if (outf) *(float4*)(outf + base) = make_float4(y0, y1, y2, y3);
}

// ---------------- GEMM: C[M,N] = A[M,K](bf16) * BT[N,K]^T(bf16) + bias -------
// mode 0: out bf16 = (acc+bias)*scale
// mode 1: out bf16 = gelu(acc+bias)
// mode 2: out fp32 = acc+bias+resid
__global__ __launch_bounds__(256)
void gemm_bt(const u16* __restrict__ A, const u16* __restrict__ BT,
             const float* __restrict__ bias, void* __restrict__ out,
             const float* __restrict__ resid, int M, int N, int K,
             int mode, float scale) {
  __shared__ __align__(16) u16 As[128 * 32];
  __shared__ __align__(16) u16 Bs[128 * 32];
  int tid = threadIdx.x;
  int lane = tid & 63, w = tid >> 6;
  int wm = w >> 1, wn = w & 1;
  int g = lane >> 4, lr = lane & 15;
  int m0 = blockIdx.y * 128, n0 = blockIdx.x * 128;

  f32x4 acc[4][4];
#pragma unroll
  for (int mt = 0; mt < 4; ++mt)
#pragma unroll
    for (int nt = 0; nt < 4; ++nt) {
      acc[mt][nt][0] = 0.f; acc[mt][nt][1] = 0.f;
      acc[mt][nt][2] = 0.f; acc[mt][nt][3] = 0.f;
    }

  int c1 = tid, c2 = tid + 256;
  const size_t ar1 = (size_t)(m0 + (c1 >> 2)) * K + (c1 & 3) * 8;
  const size_t ar2 = (size_t)(m0 + (c2 >> 2)) * K + (c2 & 3) * 8;
  const size_t br1 = (size_t)(n0 + (c1 >> 2)) * K + (c1 & 3) * 8;
  const size_t br2 = (size_t)(n0 + (c2 >> 2)) * K + (c2 & 3) * 8;

  for (int k0 = 0; k0 < K; k0 += 32) {
    uint4 a1 = *(const uint4*)(A + ar1 + k0);
    uint4 a2 = *(const uint4*)(A + ar2 + k0);
    uint4 b1 = *(const uint4*)(BT + br1 + k0);
    uint4 b2 = *(const uint4*)(BT + br2 + k0);
    __syncthreads();
    *(uint4*)(As + c1 * 8) = a1;
    *(uint4*)(As + c2 * 8) = a2;
    *(uint4*)(Bs + c1 * 8) = b1;
    *(uint4*)(Bs + c2 * 8) = b2;
    __syncthreads();
    bf16x8 af[4], bfr[4];
#pragma unroll
    for (int mt = 0; mt < 4; ++mt)
      af[mt] = *(const bf16x8*)(As + (wm * 64 + mt * 16 + lr) * 32 + g * 8);
#pragma unroll
    for (int nt = 0; nt < 4; ++nt)
      bfr[nt] = *(const bf16x8*)(Bs + (wn * 64 + nt * 16 + lr) * 32 + g * 8);
#pragma unroll
    for (int mt = 0; mt < 4; ++mt)
#pragma unroll
      for (int nt = 0; nt < 4; ++nt)
        acc[mt][nt] = __builtin_amdgcn_mfma_f32_16x16x32_bf16(af[mt], bfr[nt], acc[mt][nt], 0, 0, 0);
  }

#pragma unroll
  for (int mt = 0; mt < 4; ++mt) {
    int row = m0 + wm * 64 + mt * 16 + g * 4;
#pragma unroll
    for (int nt = 0; nt < 4; ++nt) {
      int col = n0 + wn * 64 + nt * 16 + lr;
      float bcol = bias[col];
#pragma unroll
      for (int r = 0; r < 4; ++r) {
        float vacc = acc[mt][nt][r] + bcol;
        size_t idx = (size_t)(row + r) * N + col;
        if (mode == 0)      ((u16*)out)[idx] = f2bf(vacc * scale);
        else if (mode == 1) ((u16*)out)[idx] = f2bf(geluf(vacc));
        else                ((float*)out)[idx] = vacc + resid[idx];
      }
    }
  }
}

// ---------------- flash attention (bf16 QKV, fp32 softmax) -------------------
// Q pre-scaled by 1/8. Layout [B*S, E], head h occupies cols h*64..h*64+63.
__global__ __launch_bounds__(256)
void attn_kernel(const u16* __restrict__ Q, const u16* __restrict__ Kb,
                 const u16* __restrict__ Vb, u16* __restrict__ ctx) {
  __shared__ __align__(16) u16 Kt[64 * 72];
  __shared__ __align__(16) u16 VT[64 * 72];
  __shared__ __align__(16) u16 Pw[4][16 * 72];
  int tid = threadIdx.x, lane = tid & 63, w = tid >> 6;
  int g = lane >> 4, lr = lane & 15;
  int bh = blockIdx.y, b = bh >> 4, h = bh & 15;
  int q0 = blockIdx.x * 64;
  const size_t headoff = (size_t)b * SEQ * EMB + (size_t)h * HDIM;
  const u16* Qh = Q + headoff;
  const u16* Kh = Kb + headoff;
  const u16* Vh = Vb + headoff;

  // Q fragments (A-layout): row = q0 + w*16 + (lane&15), k = kk*32 + g*8 + j
  bf16x8 qf[2];
  {
    int s = q0 + w * 16 + lr;
#pragma unroll
    for (int kk = 0; kk < 2; ++kk)
      qf[kk] = *(const bf16x8*)(Qh + (size_t)s * EMB + kk * 32 + g * 8);
  }

  float mrow[4], lrow[4];
  f32x4 oacc[4];
#pragma unroll
  for (int r = 0; r < 4; ++r) { mrow[r] = -1e30f; lrow[r] = 0.f; }
#pragma unroll
  for (int nt = 0; nt < 4; ++nt) {
    oacc[nt][0] = 0.f; oacc[nt][1] = 0.f; oacc[nt][2] = 0.f; oacc[nt][3] = 0.f;
  }

  for (int t0 = 0; t0 <= q0; t0 += 64) {
    __syncthreads();
    // stage K tile [t][d] and V^T tile [d][t] (stride 72 to spread banks)
#pragma unroll
    for (int cc = 0; cc < 2; ++cc) {
      int c = tid + cc * 256;
      int t = c >> 3, d0 = (c & 7) * 8;
      uint4 kv = *(const uint4*)(Kh + (size_t)(t0 + t) * EMB + d0);
      *(uint4*)(&Kt[t * 72 + d0]) = kv;
      uint4 vv = *(const uint4*)(Vh + (size_t)(t0 + t) * EMB + d0);
      union { uint4 u; u16 s[8]; } uu; uu.u = vv;
#pragma unroll
      for (int j = 0; j < 8; ++j)
        VT[(d0 + j) * 72 + t] = uu.s[j];
    }
    __syncthreads();

    // scores: S = Q K^T (Q pre-scaled). C-layout: row=g*4+r, col=nt*16+lr
    f32x4 sacc[4];
#pragma unroll
    for (int nt = 0; nt < 4; ++nt) {
      sacc[nt][0] = 0.f; sacc[nt][1] = 0.f; sacc[nt][2] = 0.f; sacc[nt][3] = 0.f;
    }
#pragma unroll
    for (int kk = 0; kk < 2; ++kk)
#pragma unroll
      for (int nt = 0; nt < 4; ++nt) {
        bf16x8 bfr = *(const bf16x8*)(&Kt[(nt * 16 + lr) * 72 + kk * 32 + g * 8]);
        sacc[nt] = __builtin_amdgcn_mfma_f32_16x16x32_bf16(qf[kk], bfr, sacc[nt], 0, 0, 0);
      }

    int qbase = q0 + w * 16 + g * 4;
    float mnew[4], alpha[4];
#pragma unroll
    for (int r = 0; r < 4; ++r) {
      float mx = -1e30f;
#pragma unroll
      for (int nt = 0; nt < 4; ++nt) {
        int t = t0 + nt * 16 + lr;
        float sv = sacc[nt][r];
        if (t > qbase + r) { sv = -1e30f; sacc[nt][r] = sv; }
        mx = fmaxf(mx, sv);
      }
#pragma unroll
      for (int off = 1; off < 16; off <<= 1)
        mx = fmaxf(mx, __shfl_xor(mx, off));
      mnew[r] = fmaxf(mrow[r], mx);
      alpha[r] = __expf(mrow[r] - mnew[r]);
      mrow[r] = mnew[r];
    }

#pragma unroll
    for (int r = 0; r < 4; ++r) {
      float rs = 0.f;
#pragma unroll
      for (int nt = 0; nt < 4; ++nt) {
        float p = __expf(sacc[nt][r] - mnew[r]);
        rs += p;
        Pw[w][(g * 4 + r) * 72 + nt * 16 + lr] = f2bf(p);
      }
#pragma unroll
      for (int off = 1; off < 16; off <<= 1)
        rs += __shfl_xor(rs, off);
      lrow[r] = lrow[r] * alpha[r] + rs;
#pragma unroll
      for (int nt = 0; nt < 4; ++nt)
        oacc[nt][r] *= alpha[r];
    }
    __syncthreads();

    // O += P V  (P A-layout from LDS, V^T B-layout from LDS)
#pragma unroll
    for (int kk = 0; kk < 2; ++kk) {
      bf16x8 pf = *(const bf16x8*)(&Pw[w][lr * 72 + kk * 32 + g * 8]);
#pragma unroll
      for (int nt = 0; nt < 4; ++nt) {
        bf16x8 vf = *(const bf16x8*)(&VT[(nt * 16 + lr) * 72 + kk * 32 + g * 8]);
        oacc[nt] = __builtin_amdgcn_mfma_f32_16x16x32_bf16(pf, vf, oacc[nt], 0, 0, 0);
      }
    }
  }

  // normalize + store ctx (bf16)
  int srow = q0 + w * 16 + g * 4;
#pragma unroll
  for (int nt = 0; nt < 4; ++nt) {
    int col = h * HDIM + nt * 16 + lr;
#pragma unroll
    for (int r = 0; r < 4; ++r) {
      float o = oacc[nt][r] / lrow[r];
      ctx[((size_t)b * SEQ + srow + r) * EMB + col] = f2bf(o);
    }
  }
}

// ---------------- launch ----------------
extern "C" void kernel_launch(void* const* d_in, const int* in_sizes, int n_in,
                              void* d_out, int out_size, void* d_ws, size_t ws_size,
                              hipStream_t stream) {
  const float* x    = (const float*)d_in[0];
  const float* Wq   = (const float*)d_in[2];
  const float* bq   = (const float*)d_in[3];
  const float* Wk   = (const float*)d_in[4];
  const float* bk   = (const float*)d_in[5];
  const float* Wv   = (const float*)d_in[6];
  const float* bv   = (const float*)d_in[7];
  const float* Wo   = (const float*)d_in[8];
  const float* bo   = (const float*)d_in[9];
  const float* W1   = (const float*)d_in[10];
  const float* b1   = (const float*)d_in[11];
  const float* W2   = (const float*)d_in[12];
  const float* b2   = (const float*)d_in[13];
  const float* ln1g = (const float*)d_in[14];
  const float* ln1b = (const float*)d_in[15];
  const float* ln2g = (const float*)d_in[16];
  const float* ln2b = (const float*)d_in[17];

  char* ws = (char*)d_ws;
  u16* WqT  = (u16*)(ws + ((size_t)0 << 20));
  u16* WkT  = (u16*)(ws + ((size_t)2 << 20));
  u16* WvT  = (u16*)(ws + ((size_t)4 << 20));
  u16* WoT  = (u16*)(ws + ((size_t)6 << 20));
  u16* W1T  = (u16*)(ws + ((size_t)8 << 20));
  u16* W2T  = (u16*)(ws + ((size_t)16 << 20));
  u16* xb   = (u16*)(ws + ((size_t)24 << 20));   // ln1 out bf16; later reused as x2b
  u16* Qb   = (u16*)(ws + ((size_t)32 << 20));
  u16* Kb   = (u16*)(ws + ((size_t)40 << 20));
  u16* Vb   = (u16*)(ws + ((size_t)48 << 20));
  u16* ctxb = (u16*)(ws + ((size_t)56 << 20));
  float* xpa = (float*)(ws + ((size_t)32 << 20)); // x + attn_out (overlaps dead Qb/Kb)
  float* x2f = (float*)(ws + ((size_t)48 << 20)); // ln2 out fp32 (overlaps dead Vb/ctx)
  u16* x2b  = xb;                                 // ln2 out bf16 (overlaps dead xb)
  u16* h1   = (u16*)(ws + ((size_t)64 << 20));    // gelu(ffn1) bf16, 32MB

  dim3 blk(256);
  const int M = NBATCH * SEQ; // 4096

  // weight transposes (fp32 -> bf16, [K,N] -> [N,K])
  wtrans_kernel<<<dim3(32, 32), blk, 0, stream>>>(Wq, WqT, EMB, EMB);
  wtrans_kernel<<<dim3(32, 32), blk, 0, stream>>>(Wk, WkT, EMB, EMB);
  wtrans_kernel<<<dim3(32, 32), blk, 0, stream>>>(Wv, WvT, EMB, EMB);
  wtrans_kernel<<<dim3(32, 32), blk, 0, stream>>>(Wo, WoT, EMB, EMB);
  wtrans_kernel<<<dim3(128, 32), blk, 0, stream>>>(W1, W1T, EMB, FFDIM);
  wtrans_kernel<<<dim3(32, 128), blk, 0, stream>>>(W2, W2T, FFDIM, EMB);

  // LN1
  ln_kernel<<<M, blk, 0, stream>>>(x, ln1g, ln1b, xb, nullptr);

  // QKV projections (Q pre-scaled by 1/sqrt(64))
  gemm_bt<<<dim3(EMB / 128, M / 128), blk, 0, stream>>>(xb, WqT, bq, Qb, nullptr, M, EMB, EMB, 0, 0.125f);
  gemm_bt<<<dim3(EMB / 128, M / 128), blk, 0, stream>>>(xb, WkT, bk, Kb, nullptr, M, EMB, EMB, 0, 1.0f);
  gemm_bt<<<dim3(EMB / 128, M / 128), blk, 0, stream>>>(xb, WvT, bv, Vb, nullptr, M, EMB, EMB, 0, 1.0f);

  // attention
  attn_kernel<<<dim3(SEQ / 64, NBATCH * NHEAD), blk, 0, stream>>>(Qb, Kb, Vb, ctxb);

  // output projection + residual -> xpa = x + attn_out (fp32)
  gemm_bt<<<dim3(EMB / 128, M / 128), blk, 0, stream>>>(ctxb, WoT, bo, xpa, x, M, EMB, EMB, 2, 1.0f);

  // LN2 -> x2f fp32 + x2b bf16
  ln_kernel<<<M, blk, 0, stream>>>(xpa, ln2g, ln2b, x2b, x2f);

  // FFN1 + exact GELU -> h1 bf16
  gemm_bt<<<dim3(FFDIM / 128, M / 128), blk, 0, stream>>>(x2b, W1T, b1, h1, nullptr, M, FFDIM, EMB, 1, 1.0f);

  // FFN2 + residual -> d_out fp32
  gemm_bt<<<dim3(EMB / 128, M / 128), blk, 0, stream>>>(h1, W2T, b2, (float*)d_out, x2f, M, EMB, FFDIM, 2, 1.0f);
}

// Round 2
// 574.023 us; speedup vs baseline: 1.1152x; 1.1152x over previous
//
#include <hip/hip_runtime.h>
#include <cmath>

typedef unsigned short u16;
typedef unsigned int u32;
typedef __bf16 bf16x8 __attribute__((ext_vector_type(8)));
typedef float f32x4 __attribute__((ext_vector_type(4)));

#define SEQ 2048
#define EMB 1024
#define NHEAD 16
#define HDIM 64
#define FFDIM 4096
#define NBATCH 2

__device__ __forceinline__ u16 f2bf(float f) {
  u32 u = __float_as_uint(f);
  u32 r = u + 0x7fffu + ((u >> 16) & 1u);
  return (u16)(r >> 16);
}

__device__ __forceinline__ float geluf(float x) {
  return 0.5f * x * (1.0f + erff(x * 0.70710678118654752f));
}

// async global->LDS, 16B per lane. LDS dest must be wave-uniform base + lane*16.
__device__ __forceinline__ void gload16(const void* g, void* l) {
  __builtin_amdgcn_global_load_lds(
      (const __attribute__((address_space(1))) unsigned int*)g,
      (__attribute__((address_space(3))) unsigned int*)l, 16, 0, 0);
}

// ---------------- weight transpose + fp32->bf16 ----------------
// W [K,N] fp32 -> WT [N,K] bf16
__global__ __launch_bounds__(256)
void wtrans_kernel(const float* __restrict__ W, u16* __restrict__ WT, int K, int N) {
  __shared__ float tile[32][33];
  int tx = threadIdx.x & 31, ty = threadIdx.x >> 5;
  int n0 = blockIdx.x * 32, k0 = blockIdx.y * 32;
#pragma unroll
  for (int i = 0; i < 32; i += 8)
    tile[ty + i][tx] = W[(size_t)(k0 + ty + i) * N + (n0 + tx)];
  __syncthreads();
#pragma unroll
  for (int i = 0; i < 32; i += 8)
    WT[(size_t)(n0 + ty + i) * K + (k0 + tx)] = f2bf(tile[tx][ty + i]);
}

// ---------------- V transpose per head: Vb [B*S,E] -> Vt [B*H, 64, SEQ] ------
__global__ __launch_bounds__(256)
void vtrans_kernel(const u16* __restrict__ Vb, u16* __restrict__ Vt) {
  __shared__ u16 tile[64 * 72];
  int bh = blockIdx.y, b = bh >> 4, h = bh & 15;
  int s0 = blockIdx.x * 64;
  const u16* src = Vb + (size_t)b * SEQ * EMB + (size_t)h * HDIM;
  int tid = threadIdx.x;
#pragma unroll
  for (int cc = 0; cc < 2; ++cc) {
    int c = tid + cc * 256;
    int s = c >> 3, d0 = (c & 7) * 8;
    uint4 v = *(const uint4*)(src + (size_t)(s0 + s) * EMB + d0);
    *(uint4*)(&tile[s * 72 + d0]) = v;
  }
  __syncthreads();
  u16* dst = Vt + (size_t)bh * HDIM * SEQ;
#pragma unroll
  for (int cc = 0; cc < 2; ++cc) {
    int c = tid + cc * 256;
    int d = c >> 3, t0l = (c & 7) * 8;
    union { uint4 u; u16 s[8]; } ou;
#pragma unroll
    for (int j = 0; j < 8; ++j) ou.s[j] = tile[(t0l + j) * 72 + d];
    *(uint4*)(dst + (size_t)d * SEQ + s0 + t0l) = ou.u;
  }
}

// ---------------- layernorm (fp32 in, bf16 out + optional fp32 out) -----------
__global__ __launch_bounds__(256)
void ln_kernel(const float* __restrict__ in, const float* __restrict__ gamma,
               const float* __restrict__ beta, u16* __restrict__ outb,
               float* __restrict__ outf) {
  int row = blockIdx.x, tid = threadIdx.x;
  size_t base = (size_t)row * EMB + tid * 4;
  float4 v = *(const float4*)(in + base);
  float s = v.x + v.y + v.z + v.w;
  float q = v.x * v.x + v.y * v.y + v.z * v.z + v.w * v.w;
#pragma unroll
  for (int off = 1; off < 64; off <<= 1) {
    s += __shfl_xor(s, off);
    q += __shfl_xor(q, off);
  }
  __shared__ float ss[4], sq[4];
  int w = tid >> 6, lane = tid & 63;
  if (lane == 0) { ss[w] = s; sq[w] = q; }
  __syncthreads();
  float ts = ss[0] + ss[1] + ss[2] + ss[3];
  float tq = sq[0] + sq[1] + sq[2] + sq[3];
  float mean = ts * (1.0f / EMB);
  float var = tq * (1.0f / EMB) - mean * mean;
  float rstd = rsqrtf(var + 1e-5f);
  float4 g4 = *(const float4*)(gamma + tid * 4);
  float4 b4 = *(const float4*)(beta + tid * 4);
  float y0 = (v.x - mean) * rstd * g4.x + b4.x;
  float y1 = (v.y - mean) * rstd * g4.y + b4.y;
  float y2 = (v.z - mean) * rstd * g4.z + b4.z;
  float y3 = (v.w - mean) * rstd * g4.w + b4.w;
  ushort4 ob;
  ob.x = f2bf(y0); ob.y = f2bf(y1); ob.z = f2bf(y2); ob.w = f2bf(y3);
  *(ushort4*)(outb + base) = ob;
  if (outf) *(float4*)(outf + base) = make_float4(y0, y1, y2, y3);
}

// ---------------- GEMM: C[M,N] = A[M,K](bf16) * BT[N,K]^T(bf16) + bias -------
// mode 0: out bf16 = (acc+bias)*scale
// mode 1: out bf16 = gelu(acc+bias)
// mode 2: out fp32 = acc+bias+resid
__global__ __launch_bounds__(256)
void gemm_bt(const u16* __restrict__ A, const u16* __restrict__ BT,
             const float* __restrict__ bias, void* __restrict__ out,
             const float* __restrict__ resid, int M, int N, int K,
             int mode, float scale) {
  __shared__ __align__(16) u16 As[128 * 32];
  __shared__ __align__(16) u16 Bs[128 * 32];
  int tid = threadIdx.x;
  int lane = tid & 63, w = tid >> 6;
  int wm = w >> 1, wn = w & 1;
  int g = lane >> 4, lr = lane & 15;
  int m0 = blockIdx.y * 128, n0 = blockIdx.x * 128;

  f32x4 acc[4][4];
#pragma unroll
  for (int mt = 0; mt < 4; ++mt)
#pragma unroll
    for (int nt = 0; nt < 4; ++nt) {
      acc[mt][nt][0] = 0.f; acc[mt][nt][1] = 0.f;
      acc[mt][nt][2] = 0.f; acc[mt][nt][3] = 0.f;
    }

  int c1 = tid, c2 = tid + 256;
  const size_t ar1 = (size_t)(m0 + (c1 >> 2)) * K + (c1 & 3) * 8;
  const size_t ar2 = (size_t)(m0 + (c2 >> 2)) * K + (c2 & 3) * 8;
  const size_t br1 = (size_t)(n0 + (c1 >> 2)) * K + (c1 & 3) * 8;
  const size_t br2 = (size_t)(n0 + (c2 >> 2)) * K + (c2 & 3) * 8;

  for (int k0 = 0; k0 < K; k0 += 32) {
    __syncthreads();  // all waves done reading LDS of previous tile
    gload16(A + ar1 + k0, As + c1 * 8);
    gload16(A + ar2 + k0, As + c2 * 8);
    gload16(BT + br1 + k0, Bs + c1 * 8);
    gload16(BT + br2 + k0, Bs + c2 * 8);
    __syncthreads();  // compiler drains vmcnt(0) before s_barrier -> LDS ready
    bf16x8 af[4], bfr[4];
#pragma unroll
    for (int mt = 0; mt < 4; ++mt)
      af[mt] = *(const bf16x8*)(As + (wm * 64 + mt * 16 + lr) * 32 + g * 8);
#pragma unroll
    for (int nt = 0; nt < 4; ++nt)
      bfr[nt] = *(const bf16x8*)(Bs + (wn * 64 + nt * 16 + lr) * 32 + g * 8);
#pragma unroll
    for (int mt = 0; mt < 4; ++mt)
#pragma unroll
      for (int nt = 0; nt < 4; ++nt)
        acc[mt][nt] = __builtin_amdgcn_mfma_f32_16x16x32_bf16(af[mt], bfr[nt], acc[mt][nt], 0, 0, 0);
  }

#pragma unroll
  for (int mt = 0; mt < 4; ++mt) {
    int row = m0 + wm * 64 + mt * 16 + g * 4;
#pragma unroll
    for (int nt = 0; nt < 4; ++nt) {
      int col = n0 + wn * 64 + nt * 16 + lr;
      float bcol = bias[col];
#pragma unroll
      for (int r = 0; r < 4; ++r) {
        float vacc = acc[mt][nt][r] + bcol;
        size_t idx = (size_t)(row + r) * N + col;
        if (mode == 0)      ((u16*)out)[idx] = f2bf(vacc * scale);
        else if (mode == 1) ((u16*)out)[idx] = f2bf(geluf(vacc));
        else                ((float*)out)[idx] = vacc + resid[idx];
      }
    }
  }
}

// ---------------- flash attention, paired q-tiles ----------------------------
// Q pre-scaled by 1/8. Q,K: [B*S, E] bf16 (head h = cols h*64..). Vt: [B*H,64,SEQ].
// Block (p, bh) handles q-tiles p and 31-p  -> exactly 33 tile-iterations each.
__shared__ __align__(16) u16 attn_Kt[64 * 64];
__shared__ __align__(16) u16 attn_VT[64 * 64];
__shared__ __align__(16) u16 attn_Pw[2][4][16 * 72];

template <int S0>
__device__ __forceinline__ void attn_tile(
    int t0, const int* q0, int w, int g, int lr,
    bf16x8 (&qf)[2][2], float (&mrow)[2][4], float (&lrow)[2][4],
    f32x4 (&oacc)[2][4]) {
  f32x4 sacc[2][4];
#pragma unroll
  for (int s = S0; s < 2; ++s)
#pragma unroll
    for (int nt = 0; nt < 4; ++nt) {
      sacc[s][nt][0] = 0.f; sacc[s][nt][1] = 0.f;
      sacc[s][nt][2] = 0.f; sacc[s][nt][3] = 0.f;
    }
  // scores for both states sharing the K fragment
#pragma unroll
  for (int kk = 0; kk < 2; ++kk)
#pragma unroll
    for (int nt = 0; nt < 4; ++nt) {
      bf16x8 bfr = *(const bf16x8*)(&attn_Kt[(nt * 16 + lr) * 64 + kk * 32 + g * 8]);
      if (S0 == 0)
        sacc[0][nt] = __builtin_amdgcn_mfma_f32_16x16x32_bf16(qf[0][kk], bfr, sacc[0][nt], 0, 0, 0);
      sacc[1][nt] = __builtin_amdgcn_mfma_f32_16x16x32_bf16(qf[1][kk], bfr, sacc[1][nt], 0, 0, 0);
    }

#pragma unroll
  for (int s = S0; s < 2; ++s) {
    bool diag = (t0 == q0[s]);  // wave-uniform
#pragma unroll
    for (int r = 0; r < 4; ++r) {
      if (diag) {
#pragma unroll
        for (int nt = 0; nt < 4; ++nt)
          if (nt * 16 + lr > w * 16 + g * 4 + r) sacc[s][nt][r] = -1e30f;
      }
      float mx = fmaxf(fmaxf(sacc[s][0][r], sacc[s][1][r]),
                       fmaxf(sacc[s][2][r], sacc[s][3][r]));
#pragma unroll
      for (int off = 1; off < 16; off <<= 1)
        mx = fmaxf(mx, __shfl_xor(mx, off));
      float mnew = fmaxf(mrow[s][r], mx);
      float alpha = __expf(mrow[s][r] - mnew);
      mrow[s][r] = mnew;
      float rs = 0.f;
#pragma unroll
      for (int nt = 0; nt < 4; ++nt) {
        float pv = __expf(sacc[s][nt][r] - mnew);
        rs += pv;
        attn_Pw[s][w][(g * 4 + r) * 72 + nt * 16 + lr] = f2bf(pv);
      }
#pragma unroll
      for (int off = 1; off < 16; off <<= 1)
        rs += __shfl_xor(rs, off);
      lrow[s][r] = lrow[s][r] * alpha + rs;
#pragma unroll
      for (int nt = 0; nt < 4; ++nt)
        oacc[s][nt][r] *= alpha;
    }
  }

  // O += P V, sharing the V fragment. Pw is per-wave private: no barrier needed.
#pragma unroll
  for (int kk = 0; kk < 2; ++kk) {
    bf16x8 pf0, pf1;
    if (S0 == 0) pf0 = *(const bf16x8*)(&attn_Pw[0][w][lr * 72 + kk * 32 + g * 8]);
    pf1 = *(const bf16x8*)(&attn_Pw[1][w][lr * 72 + kk * 32 + g * 8]);
#pragma unroll
    for (int nt = 0; nt < 4; ++nt) {
      bf16x8 vf = *(const bf16x8*)(&attn_VT[(nt * 16 + lr) * 64 + kk * 32 + g * 8]);
      if (S0 == 0)
        oacc[0][nt] = __builtin_amdgcn_mfma_f32_16x16x32_bf16(pf0, vf, oacc[0][nt], 0, 0, 0);
      oacc[1][nt] = __builtin_amdgcn_mfma_f32_16x16x32_bf16(pf1, vf, oacc[1][nt], 0, 0, 0);
    }
  }
}

__global__ __launch_bounds__(256)
void attn2_kernel(const u16* __restrict__ Q, const u16* __restrict__ Kb,
                  const u16* __restrict__ Vt, u16* __restrict__ ctx) {
  int tid = threadIdx.x, lane = tid & 63, w = tid >> 6;
  int g = lane >> 4, lr = lane & 15;
  int bh = blockIdx.y, b = bh >> 4, h = bh & 15;
  int q0[2];
  q0[0] = blockIdx.x * 64;
  q0[1] = (SEQ / 64 - 1 - blockIdx.x) * 64;
  const size_t headoff = (size_t)b * SEQ * EMB + (size_t)h * HDIM;
  const u16* Qh = Q + headoff;
  const u16* Kh = Kb + headoff;
  const u16* Vth = Vt + (size_t)bh * HDIM * SEQ;

  bf16x8 qf[2][2];
#pragma unroll
  for (int s = 0; s < 2; ++s)
#pragma unroll
    for (int kk = 0; kk < 2; ++kk)
      qf[s][kk] = *(const bf16x8*)(Qh + (size_t)(q0[s] + w * 16 + lr) * EMB + kk * 32 + g * 8);

  float mrow[2][4], lrow[2][4];
  f32x4 oacc[2][4];
#pragma unroll
  for (int s = 0; s < 2; ++s)
#pragma unroll
    for (int r = 0; r < 4; ++r) { mrow[s][r] = -1e30f; lrow[s][r] = 0.f; }
#pragma unroll
  for (int s = 0; s < 2; ++s)
#pragma unroll
    for (int nt = 0; nt < 4; ++nt) {
      oacc[s][nt][0] = 0.f; oacc[s][nt][1] = 0.f;
      oacc[s][nt][2] = 0.f; oacc[s][nt][3] = 0.f;
    }

  int c1 = tid, c2 = tid + 256;
  for (int t0 = 0; t0 <= q0[1]; t0 += 64) {
    __syncthreads();
    gload16(Kh + (size_t)(t0 + (c1 >> 3)) * EMB + (c1 & 7) * 8, attn_Kt + c1 * 8);
    gload16(Kh + (size_t)(t0 + (c2 >> 3)) * EMB + (c2 & 7) * 8, attn_Kt + c2 * 8);
    gload16(Vth + (size_t)(c1 >> 3) * SEQ + t0 + (c1 & 7) * 8, attn_VT + c1 * 8);
    gload16(Vth + (size_t)(c2 >> 3) * SEQ + t0 + (c2 & 7) * 8, attn_VT + c2 * 8);
    __syncthreads();  // vmcnt(0) drain + barrier -> tiles ready

    if (t0 <= q0[0])
      attn_tile<0>(t0, q0, w, g, lr, qf, mrow, lrow, oacc);
    else
      attn_tile<1>(t0, q0, w, g, lr, qf, mrow, lrow, oacc);
  }

#pragma unroll
  for (int s = 0; s < 2; ++s) {
    int srow = q0[s] + w * 16 + g * 4;
#pragma unroll
    for (int nt = 0; nt < 4; ++nt) {
      int col = h * HDIM + nt * 16 + lr;
#pragma unroll
      for (int r = 0; r < 4; ++r) {
        float o = oacc[s][nt][r] / lrow[s][r];
        ctx[((size_t)b * SEQ + srow + r) * EMB + col] = f2bf(o);
      }
    }
  }
}

// ---------------- launch ----------------
extern "C" void kernel_launch(void* const* d_in, const int* in_sizes, int n_in,
                              void* d_out, int out_size, void* d_ws, size_t ws_size,
                              hipStream_t stream) {
  const float* x    = (const float*)d_in[0];
  const float* Wq   = (const float*)d_in[2];
  const float* bq   = (const float*)d_in[3];
  const float* Wk   = (const float*)d_in[4];
  const float* bk   = (const float*)d_in[5];
  const float* Wv   = (const float*)d_in[6];
  const float* bv   = (const float*)d_in[7];
  const float* Wo   = (const float*)d_in[8];
  const float* bo   = (const float*)d_in[9];
  const float* W1   = (const float*)d_in[10];
  const float* b1   = (const float*)d_in[11];
  const float* W2   = (const float*)d_in[12];
  const float* b2   = (const float*)d_in[13];
  const float* ln1g = (const float*)d_in[14];
  const float* ln1b = (const float*)d_in[15];
  const float* ln2g = (const float*)d_in[16];
  const float* ln2b = (const float*)d_in[17];

  char* ws = (char*)d_ws;
  u16* WqT  = (u16*)(ws + ((size_t)0 << 20));
  u16* WkT  = (u16*)(ws + ((size_t)2 << 20));
  u16* WvT  = (u16*)(ws + ((size_t)4 << 20));
  u16* WoT  = (u16*)(ws + ((size_t)6 << 20));
  u16* W1T  = (u16*)(ws + ((size_t)8 << 20));
  u16* W2T  = (u16*)(ws + ((size_t)16 << 20));
  u16* xb   = (u16*)(ws + ((size_t)24 << 20));   // ln1 out bf16; later reused as x2b
  u16* Qb   = (u16*)(ws + ((size_t)32 << 20));
  u16* Kb   = (u16*)(ws + ((size_t)40 << 20));
  u16* Vb   = (u16*)(ws + ((size_t)48 << 20));
  u16* ctxb = (u16*)(ws + ((size_t)56 << 20));
  float* xpa = (float*)(ws + ((size_t)32 << 20)); // x + attn_out (overlaps dead Qb/Kb)
  float* x2f = (float*)(ws + ((size_t)48 << 20)); // ln2 out fp32 (overlaps dead Vb/ctx)
  u16* x2b  = xb;                                 // ln2 out bf16 (overlaps dead xb)
  u16* VtG  = (u16*)(ws + ((size_t)64 << 20));    // V^T per head, 8MB (dead before h1 written)
  u16* h1   = (u16*)(ws + ((size_t)64 << 20));    // gelu(ffn1) bf16, 32MB

  dim3 blk(256);
  const int M = NBATCH * SEQ; // 4096

  // weight transposes (fp32 -> bf16, [K,N] -> [N,K])
  wtrans_kernel<<<dim3(32, 32), blk, 0, stream>>>(Wq, WqT, EMB, EMB);
  wtrans_kernel<<<dim3(32, 32), blk, 0, stream>>>(Wk, WkT, EMB, EMB);
  wtrans_kernel<<<dim3(32, 32), blk, 0, stream>>>(Wv, WvT, EMB, EMB);
  wtrans_kernel<<<dim3(32, 32), blk, 0, stream>>>(Wo, WoT, EMB, EMB);
  wtrans_kernel<<<dim3(128, 32), blk, 0, stream>>>(W1, W1T, EMB, FFDIM);
  wtrans_kernel<<<dim3(32, 128), blk, 0, stream>>>(W2, W2T, FFDIM, EMB);

  // LN1
  ln_kernel<<<M, blk, 0, stream>>>(x, ln1g, ln1b, xb, nullptr);

  // QKV projections (Q pre-scaled by 1/sqrt(64))
  gemm_bt<<<dim3(EMB / 128, M / 128), blk, 0, stream>>>(xb, WqT, bq, Qb, nullptr, M, EMB, EMB, 0, 0.125f);
  gemm_bt<<<dim3(EMB / 128, M / 128), blk, 0, stream>>>(xb, WkT, bk, Kb, nullptr, M, EMB, EMB, 0, 1.0f);
  gemm_bt<<<dim3(EMB / 128, M / 128), blk, 0, stream>>>(xb, WvT, bv, Vb, nullptr, M, EMB, EMB, 0, 1.0f);

  // V^T per head
  vtrans_kernel<<<dim3(SEQ / 64, NBATCH * NHEAD), blk, 0, stream>>>(Vb, VtG);

  // attention (paired q-tiles: uniform 33 iterations/block)
  attn2_kernel<<<dim3(SEQ / 128, NBATCH * NHEAD), blk, 0, stream>>>(Qb, Kb, VtG, ctxb);

  // output projection + residual -> xpa = x + attn_out (fp32)
  gemm_bt<<<dim3(EMB / 128, M / 128), blk, 0, stream>>>(ctxb, WoT, bo, xpa, x, M, EMB, EMB, 2, 1.0f);

  // LN2 -> x2f fp32 + x2b bf16
  ln_kernel<<<M, blk, 0, stream>>>(xpa, ln2g, ln2b, x2b, x2f);

  // FFN1 + exact GELU -> h1 bf16
  gemm_bt<<<dim3(FFDIM / 128, M / 128), blk, 0, stream>>>(x2b, W1T, b1, h1, nullptr, M, FFDIM, EMB, 1, 1.0f);

  // FFN2 + residual -> d_out fp32
  gemm_bt<<<dim3(EMB / 128, M / 128), blk, 0, stream>>>(h1, W2T, b2, (float*)d_out, x2f, M, EMB, FFDIM, 2, 1.0f);
}

// Round 3
// 509.977 us; speedup vs baseline: 1.2552x; 1.1256x over previous
//
#include <hip/hip_runtime.h>
#include <cmath>

typedef unsigned short u16;
typedef unsigned int u32;
typedef __bf16 bf16x8 __attribute__((ext_vector_type(8)));
typedef float f32x4 __attribute__((ext_vector_type(4)));

#define SEQ 2048
#define EMB 1024
#define NHEAD 16
#define HDIM 64
#define FFDIM 4096
#define NBATCH 2
#define QKVLD 3072  // fused QKV row stride

__device__ __forceinline__ u16 f2bf(float f) {
  u32 u = __float_as_uint(f);
  u32 r = u + 0x7fffu + ((u >> 16) & 1u);
  return (u16)(r >> 16);
}

__device__ __forceinline__ float geluf(float x) {
  return 0.5f * x * (1.0f + erff(x * 0.70710678118654752f));
}

// async global->LDS, 16B per lane. LDS dest must be wave-uniform base + lane*16.
__device__ __forceinline__ void gload16(const void* g, void* l) {
  __builtin_amdgcn_global_load_lds(
      (const __attribute__((address_space(1))) unsigned int*)g,
      (__attribute__((address_space(3))) unsigned int*)l, 16, 0, 0);
}

// ---------------- weight transpose + fp32->bf16 ----------------
// W [K,N] fp32 -> WT [N,K] bf16
__global__ __launch_bounds__(256)
void wtrans_kernel(const float* __restrict__ W, u16* __restrict__ WT, int K, int N) {
  __shared__ float tile[32][33];
  int tx = threadIdx.x & 31, ty = threadIdx.x >> 5;
  int n0 = blockIdx.x * 32, k0 = blockIdx.y * 32;
#pragma unroll
  for (int i = 0; i < 32; i += 8)
    tile[ty + i][tx] = W[(size_t)(k0 + ty + i) * N + (n0 + tx)];
  __syncthreads();
#pragma unroll
  for (int i = 0; i < 32; i += 8)
    WT[(size_t)(n0 + ty + i) * K + (k0 + tx)] = f2bf(tile[tx][ty + i]);
}

// ---------------- V transpose per head: QKV [B*S,3072] (V at col 2048+h*64)
// -> Vt [B*H, 64, SEQ]
__global__ __launch_bounds__(256)
void vtrans_kernel(const u16* __restrict__ QKV, u16* __restrict__ Vt) {
  __shared__ u16 tile[64 * 72];
  int bh = blockIdx.y, b = bh >> 4, h = bh & 15;
  int s0 = blockIdx.x * 64;
  const u16* src = QKV + (size_t)b * SEQ * QKVLD + 2048 + (size_t)h * HDIM;
  int tid = threadIdx.x;
#pragma unroll
  for (int cc = 0; cc < 2; ++cc) {
    int c = tid + cc * 256;
    int s = c >> 3, d0 = (c & 7) * 8;
    uint4 v = *(const uint4*)(src + (size_t)(s0 + s) * QKVLD + d0);
    *(uint4*)(&tile[s * 72 + d0]) = v;
  }
  __syncthreads();
  u16* dst = Vt + (size_t)bh * HDIM * SEQ;
#pragma unroll
  for (int cc = 0; cc < 2; ++cc) {
    int c = tid + cc * 256;
    int d = c >> 3, t0l = (c & 7) * 8;
    union { uint4 u; u16 s[8]; } ou;
#pragma unroll
    for (int j = 0; j < 8; ++j) ou.s[j] = tile[(t0l + j) * 72 + d];
    *(uint4*)(dst + (size_t)d * SEQ + s0 + t0l) = ou.u;
  }
}

// ---------------- layernorm: 1 row per wave, 4 rows per block ----------------
__global__ __launch_bounds__(256)
void ln_kernel(const float* __restrict__ in, const float* __restrict__ gamma,
               const float* __restrict__ beta, u16* __restrict__ outb,
               float* __restrict__ outf) {
  int w = threadIdx.x >> 6, lane = threadIdx.x & 63;
  int row = blockIdx.x * 4 + w;
  size_t base = (size_t)row * EMB;
  float4 v[4];
  float s = 0.f, q = 0.f;
#pragma unroll
  for (int j = 0; j < 4; ++j) {
    v[j] = *(const float4*)(in + base + j * 256 + lane * 4);
    s += v[j].x + v[j].y + v[j].z + v[j].w;
    q += v[j].x * v[j].x + v[j].y * v[j].y + v[j].z * v[j].z + v[j].w * v[j].w;
  }
#pragma unroll
  for (int off = 1; off < 64; off <<= 1) {
    s += __shfl_xor(s, off);
    q += __shfl_xor(q, off);
  }
  float mean = s * (1.0f / EMB);
  float var = q * (1.0f / EMB) - mean * mean;
  float rstd = rsqrtf(var + 1e-5f);
#pragma unroll
  for (int j = 0; j < 4; ++j) {
    int c = j * 256 + lane * 4;
    float4 g4 = *(const float4*)(gamma + c);
    float4 b4 = *(const float4*)(beta + c);
    float y0 = (v[j].x - mean) * rstd * g4.x + b4.x;
    float y1 = (v[j].y - mean) * rstd * g4.y + b4.y;
    float y2 = (v[j].z - mean) * rstd * g4.z + b4.z;
    float y3 = (v[j].w - mean) * rstd * g4.w + b4.w;
    ushort4 ob;
    ob.x = f2bf(y0); ob.y = f2bf(y1); ob.z = f2bf(y2); ob.w = f2bf(y3);
    *(ushort4*)(outb + base + c) = ob;
    if (outf) *(float4*)(outf + base + c) = make_float4(y0, y1, y2, y3);
  }
}

// ---------------- split-K reduce: out = p[z0]+p[z1]+bias+resid (fp32) --------
__global__ __launch_bounds__(256)
void reduce2_kernel(const float* __restrict__ p, size_t pstride,
                    const float* __restrict__ bias, const float* __restrict__ resid,
                    float* __restrict__ out, int ncols) {
  size_t i = ((size_t)blockIdx.x * 256 + threadIdx.x) * 4;
  float4 a = *(const float4*)(p + i);
  float4 b = *(const float4*)(p + pstride + i);
  float4 r = *(const float4*)(resid + i);
  int col = (int)(i & (size_t)(ncols - 1));
  float4 bb = *(const float4*)(bias + col);
  float4 o;
  o.x = a.x + b.x + r.x + bb.x;
  o.y = a.y + b.y + r.y + bb.y;
  o.z = a.z + b.z + r.z + bb.z;
  o.w = a.w + b.w + r.w + bb.w;
  *(float4*)(out + i) = o;
}

// ---------------- GEMM: C[M,N] = A[M,K](bf16) * BT[N,K]^T(bf16) --------------
// mode 0: out bf16 = (acc+bias)*scale
// mode 1: out bf16 = gelu(acc+bias)
// mode 2: out fp32 = acc+bias+resid
// mode 3: out bf16 = (acc+bias{q,k,v})* (col<1024 ? 0.125 : 1)   [fused QKV]
// mode 4: partial[z*pstride + idx] = acc (raw fp32, split-K)
__global__ __launch_bounds__(256)
void gemm_bt(const u16* __restrict__ A, const u16* __restrict__ BT,
             const float* __restrict__ bias, const float* __restrict__ bias2,
             const float* __restrict__ bias3, void* __restrict__ out,
             const float* __restrict__ resid, int M, int N, int K,
             int mode, float scale, int ksplit,
             float* __restrict__ partial, size_t pstride) {
  __shared__ __align__(16) u16 As[128 * 32];
  __shared__ __align__(16) u16 Bs[128 * 32];
  int tid = threadIdx.x;
  int lane = tid & 63, w = tid >> 6;
  int wm = w >> 1, wn = w & 1;
  int g = lane >> 4, lr = lane & 15;
  int m0 = blockIdx.y * 128, n0 = blockIdx.x * 128;
  int z = blockIdx.z;
  int kbeg = z * ksplit, kend = kbeg + ksplit;

  f32x4 acc[4][4];
#pragma unroll
  for (int mt = 0; mt < 4; ++mt)
#pragma unroll
    for (int nt = 0; nt < 4; ++nt) {
      acc[mt][nt][0] = 0.f; acc[mt][nt][1] = 0.f;
      acc[mt][nt][2] = 0.f; acc[mt][nt][3] = 0.f;
    }

  int c1 = tid, c2 = tid + 256;
  const size_t ar1 = (size_t)(m0 + (c1 >> 2)) * K + (c1 & 3) * 8;
  const size_t ar2 = (size_t)(m0 + (c2 >> 2)) * K + (c2 & 3) * 8;
  const size_t br1 = (size_t)(n0 + (c1 >> 2)) * K + (c1 & 3) * 8;
  const size_t br2 = (size_t)(n0 + (c2 >> 2)) * K + (c2 & 3) * 8;

  for (int k0 = kbeg; k0 < kend; k0 += 32) {
    __syncthreads();  // all waves done reading LDS of previous tile
    gload16(A + ar1 + k0, As + c1 * 8);
    gload16(A + ar2 + k0, As + c2 * 8);
    gload16(BT + br1 + k0, Bs + c1 * 8);
    gload16(BT + br2 + k0, Bs + c2 * 8);
    __syncthreads();  // vmcnt(0) drain before barrier -> LDS ready
    bf16x8 af[4], bfr[4];
#pragma unroll
    for (int mt = 0; mt < 4; ++mt)
      af[mt] = *(const bf16x8*)(As + (wm * 64 + mt * 16 + lr) * 32 + g * 8);
#pragma unroll
    for (int nt = 0; nt < 4; ++nt)
      bfr[nt] = *(const bf16x8*)(Bs + (wn * 64 + nt * 16 + lr) * 32 + g * 8);
#pragma unroll
    for (int mt = 0; mt < 4; ++mt)
#pragma unroll
      for (int nt = 0; nt < 4; ++nt)
        acc[mt][nt] = __builtin_amdgcn_mfma_f32_16x16x32_bf16(af[mt], bfr[nt], acc[mt][nt], 0, 0, 0);
  }

  float* pz = partial + (size_t)z * pstride;
#pragma unroll
  for (int mt = 0; mt < 4; ++mt) {
    int row = m0 + wm * 64 + mt * 16 + g * 4;
#pragma unroll
    for (int nt = 0; nt < 4; ++nt) {
      int col = n0 + wn * 64 + nt * 16 + lr;
      float bcol;
      if (mode == 3) {
        int which = col >> 10;
        const float* bp = (which == 0) ? bias : (which == 1) ? bias2 : bias3;
        bcol = bp[col & 1023];
      } else if (mode != 4) {
        bcol = bias[col];
      } else {
        bcol = 0.f;
      }
#pragma unroll
      for (int r = 0; r < 4; ++r) {
        float vacc = acc[mt][nt][r] + bcol;
        size_t idx = (size_t)(row + r) * N + col;
        if (mode == 0)      ((u16*)out)[idx] = f2bf(vacc * scale);
        else if (mode == 1) ((u16*)out)[idx] = f2bf(geluf(vacc));
        else if (mode == 2) ((float*)out)[idx] = vacc + resid[idx];
        else if (mode == 3) ((u16*)out)[idx] = f2bf(col < 1024 ? vacc * 0.125f : vacc);
        else                pz[idx] = vacc;
      }
    }
  }
}

// ---------------- flash attention, paired q-tiles ----------------------------
// Q pre-scaled by 1/8 in QKV. QKV: [B*S, 3072] bf16 (Q at h*64, K at 1024+h*64).
// Vt: [B*H,64,SEQ]. Block (p, bh) handles q-tiles p and 31-p -> 33 iters each.
__shared__ __align__(16) u16 attn_Kt[64 * 64];
__shared__ __align__(16) u16 attn_VT[64 * 64];
__shared__ __align__(16) u16 attn_Pw[2][4][16 * 72];

template <int S0>
__device__ __forceinline__ void attn_tile(
    int t0, const int* q0, int w, int g, int lr,
    bf16x8 (&qf)[2][2], float (&mrow)[2][4], float (&lrow)[2][4],
    f32x4 (&oacc)[2][4]) {
  f32x4 sacc[2][4];
#pragma unroll
  for (int s = S0; s < 2; ++s)
#pragma unroll
    for (int nt = 0; nt < 4; ++nt) {
      sacc[s][nt][0] = 0.f; sacc[s][nt][1] = 0.f;
      sacc[s][nt][2] = 0.f; sacc[s][nt][3] = 0.f;
    }
#pragma unroll
  for (int kk = 0; kk < 2; ++kk)
#pragma unroll
    for (int nt = 0; nt < 4; ++nt) {
      bf16x8 bfr = *(const bf16x8*)(&attn_Kt[(nt * 16 + lr) * 64 + kk * 32 + g * 8]);
      if (S0 == 0)
        sacc[0][nt] = __builtin_amdgcn_mfma_f32_16x16x32_bf16(qf[0][kk], bfr, sacc[0][nt], 0, 0, 0);
      sacc[1][nt] = __builtin_amdgcn_mfma_f32_16x16x32_bf16(qf[1][kk], bfr, sacc[1][nt], 0, 0, 0);
    }

#pragma unroll
  for (int s = S0; s < 2; ++s) {
    bool diag = (t0 == q0[s]);  // wave-uniform
#pragma unroll
    for (int r = 0; r < 4; ++r) {
      if (diag) {
#pragma unroll
        for (int nt = 0; nt < 4; ++nt)
          if (nt * 16 + lr > w * 16 + g * 4 + r) sacc[s][nt][r] = -1e30f;
      }
      float mx = fmaxf(fmaxf(sacc[s][0][r], sacc[s][1][r]),
                       fmaxf(sacc[s][2][r], sacc[s][3][r]));
#pragma unroll
      for (int off = 1; off < 16; off <<= 1)
        mx = fmaxf(mx, __shfl_xor(mx, off));
      float mnew = fmaxf(mrow[s][r], mx);
      float alpha = __expf(mrow[s][r] - mnew);
      mrow[s][r] = mnew;
      float rs = 0.f;
#pragma unroll
      for (int nt = 0; nt < 4; ++nt) {
        float pv = __expf(sacc[s][nt][r] - mnew);
        rs += pv;
        attn_Pw[s][w][(g * 4 + r) * 72 + nt * 16 + lr] = f2bf(pv);
      }
#pragma unroll
      for (int off = 1; off < 16; off <<= 1)
        rs += __shfl_xor(rs, off);
      lrow[s][r] = lrow[s][r] * alpha + rs;
#pragma unroll
      for (int nt = 0; nt < 4; ++nt)
        oacc[s][nt][r] *= alpha;
    }
  }

#pragma unroll
  for (int kk = 0; kk < 2; ++kk) {
    bf16x8 pf0, pf1;
    if (S0 == 0) pf0 = *(const bf16x8*)(&attn_Pw[0][w][lr * 72 + kk * 32 + g * 8]);
    pf1 = *(const bf16x8*)(&attn_Pw[1][w][lr * 72 + kk * 32 + g * 8]);
#pragma unroll
    for (int nt = 0; nt < 4; ++nt) {
      bf16x8 vf = *(const bf16x8*)(&attn_VT[(nt * 16 + lr) * 64 + kk * 32 + g * 8]);
      if (S0 == 0)
        oacc[0][nt] = __builtin_amdgcn_mfma_f32_16x16x32_bf16(pf0, vf, oacc[0][nt], 0, 0, 0);
      oacc[1][nt] = __builtin_amdgcn_mfma_f32_16x16x32_bf16(pf1, vf, oacc[1][nt], 0, 0, 0);
    }
  }
}

__global__ __launch_bounds__(256)
void attn2_kernel(const u16* __restrict__ QKV, const u16* __restrict__ Vt,
                  u16* __restrict__ ctx) {
  int tid = threadIdx.x, lane = tid & 63, w = tid >> 6;
  int g = lane >> 4, lr = lane & 15;
  int bh = blockIdx.y, b = bh >> 4, h = bh & 15;
  int q0[2];
  q0[0] = blockIdx.x * 64;
  q0[1] = (SEQ / 64 - 1 - blockIdx.x) * 64;
  const u16* Qh = QKV + (size_t)b * SEQ * QKVLD + (size_t)h * HDIM;
  const u16* Kh = Qh + 1024;
  const u16* Vth = Vt + (size_t)bh * HDIM * SEQ;

  bf16x8 qf[2][2];
#pragma unroll
  for (int s = 0; s < 2; ++s)
#pragma unroll
    for (int kk = 0; kk < 2; ++kk)
      qf[s][kk] = *(const bf16x8*)(Qh + (size_t)(q0[s] + w * 16 + lr) * QKVLD + kk * 32 + g * 8);

  float mrow[2][4], lrow[2][4];
  f32x4 oacc[2][4];
#pragma unroll
  for (int s = 0; s < 2; ++s)
#pragma unroll
    for (int r = 0; r < 4; ++r) { mrow[s][r] = -1e30f; lrow[s][r] = 0.f; }
#pragma unroll
  for (int s = 0; s < 2; ++s)
#pragma unroll
    for (int nt = 0; nt < 4; ++nt) {
      oacc[s][nt][0] = 0.f; oacc[s][nt][1] = 0.f;
      oacc[s][nt][2] = 0.f; oacc[s][nt][3] = 0.f;
    }

  int c1 = tid, c2 = tid + 256;
  for (int t0 = 0; t0 <= q0[1]; t0 += 64) {
    __syncthreads();
    gload16(Kh + (size_t)(t0 + (c1 >> 3)) * QKVLD + (c1 & 7) * 8, attn_Kt + c1 * 8);
    gload16(Kh + (size_t)(t0 + (c2 >> 3)) * QKVLD + (c2 & 7) * 8, attn_Kt + c2 * 8);
    gload16(Vth + (size_t)(c1 >> 3) * SEQ + t0 + (c1 & 7) * 8, attn_VT + c1 * 8);
    gload16(Vth + (size_t)(c2 >> 3) * SEQ + t0 + (c2 & 7) * 8, attn_VT + c2 * 8);
    __syncthreads();

    if (t0 <= q0[0])
      attn_tile<0>(t0, q0, w, g, lr, qf, mrow, lrow, oacc);
    else
      attn_tile<1>(t0, q0, w, g, lr, qf, mrow, lrow, oacc);
  }

#pragma unroll
  for (int s = 0; s < 2; ++s) {
    int srow = q0[s] + w * 16 + g * 4;
#pragma unroll
    for (int nt = 0; nt < 4; ++nt) {
      int col = h * HDIM + nt * 16 + lr;
#pragma unroll
      for (int r = 0; r < 4; ++r) {
        float o = oacc[s][nt][r] / lrow[s][r];
        ctx[((size_t)b * SEQ + srow + r) * EMB + col] = f2bf(o);
      }
    }
  }
}

// ---------------- launch ----------------
extern "C" void kernel_launch(void* const* d_in, const int* in_sizes, int n_in,
                              void* d_out, int out_size, void* d_ws, size_t ws_size,
                              hipStream_t stream) {
  const float* x    = (const float*)d_in[0];
  const float* Wq   = (const float*)d_in[2];
  const float* bq   = (const float*)d_in[3];
  const float* Wk   = (const float*)d_in[4];
  const float* bk   = (const float*)d_in[5];
  const float* Wv   = (const float*)d_in[6];
  const float* bv   = (const float*)d_in[7];
  const float* Wo   = (const float*)d_in[8];
  const float* bo   = (const float*)d_in[9];
  const float* W1   = (const float*)d_in[10];
  const float* b1   = (const float*)d_in[11];
  const float* W2   = (const float*)d_in[12];
  const float* b2   = (const float*)d_in[13];
  const float* ln1g = (const float*)d_in[14];
  const float* ln1b = (const float*)d_in[15];
  const float* ln2g = (const float*)d_in[16];
  const float* ln2b = (const float*)d_in[17];

  char* ws = (char*)d_ws;
  // layout (MB):
  //  0-6   WqkvT [3072,1024] bf16         (dead after QKV gemm... kept til FFN2 partial reuse)
  //  6-8   WoT
  //  8-16  W1T
  // 16-24  W2T                            (live until FFN2 gemm)
  // 24-32  xb (LN1 out bf16) -> x2b (LN2 out bf16)
  // 32-56  QKVb [4096,3072] bf16 (24MB)   -> 32-48 xpa fp32 / FFN2 partial z1
  // 56-64  ctxb [4096,1024] bf16          -> 48-64 x2f fp32 (after ctxb dead)
  // 64-72  VtG (8MB)                      -> 64-96 Wo partials -> h1 (32MB)
  u16* WqkvT = (u16*)(ws + ((size_t)0 << 20));
  u16* WoT   = (u16*)(ws + ((size_t)6 << 20));
  u16* W1T   = (u16*)(ws + ((size_t)8 << 20));
  u16* W2T   = (u16*)(ws + ((size_t)16 << 20));
  u16* xb    = (u16*)(ws + ((size_t)24 << 20));
  u16* QKVb  = (u16*)(ws + ((size_t)32 << 20));
  u16* ctxb  = (u16*)(ws + ((size_t)56 << 20));
  float* xpa = (float*)(ws + ((size_t)32 << 20));
  float* x2f = (float*)(ws + ((size_t)48 << 20));
  u16* x2b   = xb;
  u16* VtG   = (u16*)(ws + ((size_t)64 << 20));
  float* pWo = (float*)(ws + ((size_t)64 << 20));  // 2 x 16MB partials
  u16* h1    = (u16*)(ws + ((size_t)64 << 20));    // 32MB
  float* pF2 = (float*)(ws + ((size_t)0 << 20));   // z0 at 0-16; z1 at 32-48 (stride 8M floats)

  dim3 blk(256);
  const int M = NBATCH * SEQ; // 4096

  // weight transposes (fp32 -> bf16, [K,N] -> [N,K]); Wq/Wk/Wv fused into WqkvT
  wtrans_kernel<<<dim3(32, 32), blk, 0, stream>>>(Wq, WqkvT, EMB, EMB);
  wtrans_kernel<<<dim3(32, 32), blk, 0, stream>>>(Wk, WqkvT + (size_t)1024 * 1024, EMB, EMB);
  wtrans_kernel<<<dim3(32, 32), blk, 0, stream>>>(Wv, WqkvT + (size_t)2048 * 1024, EMB, EMB);
  wtrans_kernel<<<dim3(32, 32), blk, 0, stream>>>(Wo, WoT, EMB, EMB);
  wtrans_kernel<<<dim3(128, 32), blk, 0, stream>>>(W1, W1T, EMB, FFDIM);
  wtrans_kernel<<<dim3(32, 128), blk, 0, stream>>>(W2, W2T, FFDIM, EMB);

  // LN1
  ln_kernel<<<M / 4, blk, 0, stream>>>(x, ln1g, ln1b, xb, nullptr);

  // fused QKV projection (N=3072, grid 768; Q cols scaled by 1/8)
  gemm_bt<<<dim3(QKVLD / 128, M / 128), blk, 0, stream>>>(
      xb, WqkvT, bq, bk, bv, QKVb, nullptr, M, QKVLD, EMB, 3, 1.0f, EMB, nullptr, 0);

  // V^T per head
  vtrans_kernel<<<dim3(SEQ / 64, NBATCH * NHEAD), blk, 0, stream>>>(QKVb, VtG);

  // attention (paired q-tiles: uniform 33 iterations/block)
  attn2_kernel<<<dim3(SEQ / 128, NBATCH * NHEAD), blk, 0, stream>>>(QKVb, VtG, ctxb);

  // output projection, split-K=2 -> partials at 64-96MB
  gemm_bt<<<dim3(EMB / 128, M / 128, 2), blk, 0, stream>>>(
      ctxb, WoT, nullptr, nullptr, nullptr, nullptr, nullptr, M, EMB, EMB, 4, 1.0f,
      EMB / 2, pWo, (size_t)4 << 20);
  // xpa = p0 + p1 + bo + x
  reduce2_kernel<<<M * EMB / 1024, blk, 0, stream>>>(pWo, (size_t)4 << 20, bo, x, xpa, EMB);

  // LN2 -> x2f fp32 + x2b bf16
  ln_kernel<<<M / 4, blk, 0, stream>>>(xpa, ln2g, ln2b, x2b, x2f);

  // FFN1 + exact GELU -> h1 bf16 (grid 1024)
  gemm_bt<<<dim3(FFDIM / 128, M / 128), blk, 0, stream>>>(
      x2b, W1T, b1, nullptr, nullptr, h1, nullptr, M, FFDIM, EMB, 1, 1.0f, EMB, nullptr, 0);

  // FFN2, split-K=2 -> partials z0 at 0-16MB, z1 at 32-48MB
  gemm_bt<<<dim3(EMB / 128, M / 128, 2), blk, 0, stream>>>(
      h1, W2T, nullptr, nullptr, nullptr, nullptr, nullptr, M, EMB, FFDIM, 4, 1.0f,
      FFDIM / 2, pF2, (size_t)8 << 20);
  // d_out = p0 + p1 + b2 + x2f
  reduce2_kernel<<<M * EMB / 1024, blk, 0, stream>>>(pF2, (size_t)8 << 20, b2, x2f,
                                                    (float*)d_out, EMB);
}

// Round 4
// 466.866 us; speedup vs baseline: 1.3711x; 1.0923x over previous
//
#include <hip/hip_runtime.h>
#include <cmath>

typedef unsigned short u16;
typedef unsigned int u32;
typedef __bf16 bf16x8 __attribute__((ext_vector_type(8)));
typedef float f32x4 __attribute__((ext_vector_type(4)));

#define SEQ 2048
#define EMB 1024
#define NHEAD 16
#define HDIM 64
#define FFDIM 4096
#define NBATCH 2
#define QKVLD 3072  // fused QKV row stride
#define PWS 68      // Pw row stride (u16): 34 dwords -> g-groups hit banks {0,8,16,24}

// Q pre-scale folds 1/sqrt(64) and 1/ln(2) so softmax uses exp2 directly.
#define QSCALE 0.18033688011112042f

__device__ __forceinline__ u16 f2bf(float f) {
  u32 u = __float_as_uint(f);
  u32 r = u + 0x7fffu + ((u >> 16) & 1u);
  return (u16)(r >> 16);
}

__device__ __forceinline__ float ex2(float x) {
#if __has_builtin(__builtin_amdgcn_exp2f)
  return __builtin_amdgcn_exp2f(x);
#else
  return exp2f(x);
#endif
}

__device__ __forceinline__ float geluf(float x) {
  return 0.5f * x * (1.0f + erff(x * 0.70710678118654752f));
}

// async global->LDS, 16B per lane. LDS dest must be wave-uniform base + lane*16.
__device__ __forceinline__ void gload16(const void* g, void* l) {
  __builtin_amdgcn_global_load_lds(
      (const __attribute__((address_space(1))) unsigned int*)g,
      (__attribute__((address_space(3))) unsigned int*)l, 16, 0, 0);
}

// ---------------- weight transpose + fp32->bf16 ----------------
// W [K,N] fp32 -> WT [N,K] bf16
__global__ __launch_bounds__(256)
void wtrans_kernel(const float* __restrict__ W, u16* __restrict__ WT, int K, int N) {
  __shared__ float tile[32][33];
  int tx = threadIdx.x & 31, ty = threadIdx.x >> 5;
  int n0 = blockIdx.x * 32, k0 = blockIdx.y * 32;
#pragma unroll
  for (int i = 0; i < 32; i += 8)
    tile[ty + i][tx] = W[(size_t)(k0 + ty + i) * N + (n0 + tx)];
  __syncthreads();
#pragma unroll
  for (int i = 0; i < 32; i += 8)
    WT[(size_t)(n0 + ty + i) * K + (k0 + tx)] = f2bf(tile[tx][ty + i]);
}

// ---------------- V transpose per head: QKV [B*S,3072] (V at col 2048+h*64)
// -> Vt [B*H, 64, SEQ]
__global__ __launch_bounds__(256)
void vtrans_kernel(const u16* __restrict__ QKV, u16* __restrict__ Vt) {
  __shared__ u16 tile[64 * 72];
  int bh = blockIdx.y, b = bh >> 4, h = bh & 15;
  int s0 = blockIdx.x * 64;
  const u16* src = QKV + (size_t)b * SEQ * QKVLD + 2048 + (size_t)h * HDIM;
  int tid = threadIdx.x;
#pragma unroll
  for (int cc = 0; cc < 2; ++cc) {
    int c = tid + cc * 256;
    int s = c >> 3, d0 = (c & 7) * 8;
    uint4 v = *(const uint4*)(src + (size_t)(s0 + s) * QKVLD + d0);
    *(uint4*)(&tile[s * 72 + d0]) = v;
  }
  __syncthreads();
  u16* dst = Vt + (size_t)bh * HDIM * SEQ;
#pragma unroll
  for (int cc = 0; cc < 2; ++cc) {
    int c = tid + cc * 256;
    int d = c >> 3, t0l = (c & 7) * 8;
    union { uint4 u; u16 s[8]; } ou;
#pragma unroll
    for (int j = 0; j < 8; ++j) ou.s[j] = tile[(t0l + j) * 72 + d];
    *(uint4*)(dst + (size_t)d * SEQ + s0 + t0l) = ou.u;
  }
}

// ---------------- layernorm: 1 row per wave, 4 rows per block ----------------
__global__ __launch_bounds__(256)
void ln_kernel(const float* __restrict__ in, const float* __restrict__ gamma,
               const float* __restrict__ beta, u16* __restrict__ outb,
               float* __restrict__ outf) {
  int w = threadIdx.x >> 6, lane = threadIdx.x & 63;
  int row = blockIdx.x * 4 + w;
  size_t base = (size_t)row * EMB;
  float4 v[4];
  float s = 0.f, q = 0.f;
#pragma unroll
  for (int j = 0; j < 4; ++j) {
    v[j] = *(const float4*)(in + base + j * 256 + lane * 4);
    s += v[j].x + v[j].y + v[j].z + v[j].w;
    q += v[j].x * v[j].x + v[j].y * v[j].y + v[j].z * v[j].z + v[j].w * v[j].w;
  }
#pragma unroll
  for (int off = 1; off < 64; off <<= 1) {
    s += __shfl_xor(s, off);
    q += __shfl_xor(q, off);
  }
  float mean = s * (1.0f / EMB);
  float var = q * (1.0f / EMB) - mean * mean;
  float rstd = rsqrtf(var + 1e-5f);
#pragma unroll
  for (int j = 0; j < 4; ++j) {
    int c = j * 256 + lane * 4;
    float4 g4 = *(const float4*)(gamma + c);
    float4 b4 = *(const float4*)(beta + c);
    float y0 = (v[j].x - mean) * rstd * g4.x + b4.x;
    float y1 = (v[j].y - mean) * rstd * g4.y + b4.y;
    float y2 = (v[j].z - mean) * rstd * g4.z + b4.z;
    float y3 = (v[j].w - mean) * rstd * g4.w + b4.w;
    ushort4 ob;
    ob.x = f2bf(y0); ob.y = f2bf(y1); ob.z = f2bf(y2); ob.w = f2bf(y3);
    *(ushort4*)(outb + base + c) = ob;
    if (outf) *(float4*)(outf + base + c) = make_float4(y0, y1, y2, y3);
  }
}

// ---------------- split-K reduce: out = p[z0]+p[z1]+bias+resid (fp32) --------
__global__ __launch_bounds__(256)
void reduce2_kernel(const float* __restrict__ p, size_t pstride,
                    const float* __restrict__ bias, const float* __restrict__ resid,
                    float* __restrict__ out, int ncols) {
  size_t i = ((size_t)blockIdx.x * 256 + threadIdx.x) * 4;
  float4 a = *(const float4*)(p + i);
  float4 b = *(const float4*)(p + pstride + i);
  float4 r = *(const float4*)(resid + i);
  int col = (int)(i & (size_t)(ncols - 1));
  float4 bb = *(const float4*)(bias + col);
  float4 o;
  o.x = a.x + b.x + r.x + bb.x;
  o.y = a.y + b.y + r.y + bb.y;
  o.z = a.z + b.z + r.z + bb.z;
  o.w = a.w + b.w + r.w + bb.w;
  *(float4*)(out + i) = o;
}

// ---------------- GEMM: C[M,N] = A[M,K](bf16) * BT[N,K]^T(bf16) --------------
// mode 0: out bf16 = (acc+bias)*scale
// mode 1: out bf16 = gelu(acc+bias)
// mode 2: out fp32 = acc+bias+resid
// mode 3: out bf16 = (acc+bias{q,k,v})* (col<1024 ? QSCALE : 1)   [fused QKV]
// mode 4: partial[z*pstride + idx] = acc (raw fp32, split-K)
__global__ __launch_bounds__(256)
void gemm_bt(const u16* __restrict__ A, const u16* __restrict__ BT,
             const float* __restrict__ bias, const float* __restrict__ bias2,
             const float* __restrict__ bias3, void* __restrict__ out,
             const float* __restrict__ resid, int M, int N, int K,
             int mode, float scale, int ksplit,
             float* __restrict__ partial, size_t pstride) {
  __shared__ __align__(16) u16 As[128 * 32];
  __shared__ __align__(16) u16 Bs[128 * 32];
  int tid = threadIdx.x;
  int lane = tid & 63, w = tid >> 6;
  int wm = w >> 1, wn = w & 1;
  int g = lane >> 4, lr = lane & 15;
  int m0 = blockIdx.y * 128, n0 = blockIdx.x * 128;
  int z = blockIdx.z;
  int kbeg = z * ksplit, kend = kbeg + ksplit;

  f32x4 acc[4][4];
#pragma unroll
  for (int mt = 0; mt < 4; ++mt)
#pragma unroll
    for (int nt = 0; nt < 4; ++nt) {
      acc[mt][nt][0] = 0.f; acc[mt][nt][1] = 0.f;
      acc[mt][nt][2] = 0.f; acc[mt][nt][3] = 0.f;
    }

  int c1 = tid, c2 = tid + 256;
  const size_t ar1 = (size_t)(m0 + (c1 >> 2)) * K + (c1 & 3) * 8;
  const size_t ar2 = (size_t)(m0 + (c2 >> 2)) * K + (c2 & 3) * 8;
  const size_t br1 = (size_t)(n0 + (c1 >> 2)) * K + (c1 & 3) * 8;
  const size_t br2 = (size_t)(n0 + (c2 >> 2)) * K + (c2 & 3) * 8;

  for (int k0 = kbeg; k0 < kend; k0 += 32) {
    __syncthreads();  // all waves done reading LDS of previous tile
    gload16(A + ar1 + k0, As + c1 * 8);
    gload16(A + ar2 + k0, As + c2 * 8);
    gload16(BT + br1 + k0, Bs + c1 * 8);
    gload16(BT + br2 + k0, Bs + c2 * 8);
    __syncthreads();  // vmcnt(0) drain before barrier -> LDS ready
    bf16x8 af[4], bfr[4];
#pragma unroll
    for (int mt = 0; mt < 4; ++mt)
      af[mt] = *(const bf16x8*)(As + (wm * 64 + mt * 16 + lr) * 32 + g * 8);
#pragma unroll
    for (int nt = 0; nt < 4; ++nt)
      bfr[nt] = *(const bf16x8*)(Bs + (wn * 64 + nt * 16 + lr) * 32 + g * 8);
#pragma unroll
    for (int mt = 0; mt < 4; ++mt)
#pragma unroll
      for (int nt = 0; nt < 4; ++nt)
        acc[mt][nt] = __builtin_amdgcn_mfma_f32_16x16x32_bf16(af[mt], bfr[nt], acc[mt][nt], 0, 0, 0);
  }

  float* pz = partial + (size_t)z * pstride;
#pragma unroll
  for (int mt = 0; mt < 4; ++mt) {
    int row = m0 + wm * 64 + mt * 16 + g * 4;
#pragma unroll
    for (int nt = 0; nt < 4; ++nt) {
      int col = n0 + wn * 64 + nt * 16 + lr;
      float bcol;
      if (mode == 3) {
        int which = col >> 10;
        const float* bp = (which == 0) ? bias : (which == 1) ? bias2 : bias3;
        bcol = bp[col & 1023];
      } else if (mode != 4) {
        bcol = bias[col];
      } else {
        bcol = 0.f;
      }
#pragma unroll
      for (int r = 0; r < 4; ++r) {
        float vacc = acc[mt][nt][r] + bcol;
        size_t idx = (size_t)(row + r) * N + col;
        if (mode == 0)      ((u16*)out)[idx] = f2bf(vacc * scale);
        else if (mode == 1) ((u16*)out)[idx] = f2bf(geluf(vacc));
        else if (mode == 2) ((float*)out)[idx] = vacc + resid[idx];
        else if (mode == 3) ((u16*)out)[idx] = f2bf(col < 1024 ? vacc * QSCALE : vacc);
        else                pz[idx] = vacc;
      }
    }
  }
}

// ---------------- flash attention, paired q-tiles, no-max exp2 softmax -------
// Q pre-scaled by QSCALE in QKV (scores already in log2 domain).
// QKV: [B*S, 3072] bf16 (Q at h*64, K at 1024+h*64). Vt: [B*H,64,SEQ].
// Block (p, bh) handles q-tiles p and 31-p -> 33 iters each.
// K/V LDS tiles use XOR chunk swizzle: LDS chunk j of row t = global chunk j^(t&7).
// Row sums of P come from an extra MFMA against an all-ones B fragment (no
// shuffles, no online rescale -> softmax is just exp2 + bf16 pack).
__shared__ __align__(16) u16 attn_Kt[64 * 64];
__shared__ __align__(16) u16 attn_VT[64 * 64];
__shared__ __align__(16) u16 attn_Pw[2][4][16 * PWS];

template <int S0>
__device__ __forceinline__ void attn_tile(
    int t0, const int* q0, int w, int g, int lr, const bf16x8& ones,
    bf16x8 (&qf)[2][2], f32x4 (&lacc)[2], f32x4 (&oacc)[2][4]) {
  f32x4 sacc[2][4];
#pragma unroll
  for (int s = S0; s < 2; ++s)
#pragma unroll
    for (int nt = 0; nt < 4; ++nt) {
      sacc[s][nt][0] = 0.f; sacc[s][nt][1] = 0.f;
      sacc[s][nt][2] = 0.f; sacc[s][nt][3] = 0.f;
    }
  // scores (log2 domain): both states share the K fragment
#pragma unroll
  for (int kk = 0; kk < 2; ++kk)
#pragma unroll
    for (int nt = 0; nt < 4; ++nt) {
      int sw = ((kk * 4 + g) ^ lr) & 7;
      bf16x8 bfr = *(const bf16x8*)(&attn_Kt[(nt * 16 + lr) * 64 + sw * 8]);
      if (S0 == 0)
        sacc[0][nt] = __builtin_amdgcn_mfma_f32_16x16x32_bf16(qf[0][kk], bfr, sacc[0][nt], 0, 0, 0);
      sacc[1][nt] = __builtin_amdgcn_mfma_f32_16x16x32_bf16(qf[1][kk], bfr, sacc[1][nt], 0, 0, 0);
    }

  // P = exp2(S) (masked on the diagonal tile), packed to bf16 in LDS
#pragma unroll
  for (int s = S0; s < 2; ++s) {
    bool diag = (t0 == q0[s]);  // wave-uniform
#pragma unroll
    for (int r = 0; r < 4; ++r) {
#pragma unroll
      for (int nt = 0; nt < 4; ++nt) {
        float pv = ex2(sacc[s][nt][r]);
        if (diag && (nt * 16 + lr > w * 16 + g * 4 + r)) pv = 0.f;
        attn_Pw[s][w][(g * 4 + r) * PWS + nt * 16 + lr] = f2bf(pv);
      }
    }
  }

  // O += P V and l += P * 1 (row sums land in C-layout, same rows as O).
  // Pw is per-wave private: no barrier needed.
#pragma unroll
  for (int kk = 0; kk < 2; ++kk) {
    bf16x8 pf0, pf1;
    if (S0 == 0) pf0 = *(const bf16x8*)(&attn_Pw[0][w][lr * PWS + kk * 32 + g * 8]);
    pf1 = *(const bf16x8*)(&attn_Pw[1][w][lr * PWS + kk * 32 + g * 8]);
#pragma unroll
    for (int nt = 0; nt < 4; ++nt) {
      int sw = ((kk * 4 + g) ^ lr) & 7;
      bf16x8 vf = *(const bf16x8*)(&attn_VT[(nt * 16 + lr) * 64 + sw * 8]);
      if (S0 == 0)
        oacc[0][nt] = __builtin_amdgcn_mfma_f32_16x16x32_bf16(pf0, vf, oacc[0][nt], 0, 0, 0);
      oacc[1][nt] = __builtin_amdgcn_mfma_f32_16x16x32_bf16(pf1, vf, oacc[1][nt], 0, 0, 0);
    }
    if (S0 == 0)
      lacc[0] = __builtin_amdgcn_mfma_f32_16x16x32_bf16(pf0, ones, lacc[0], 0, 0, 0);
    lacc[1] = __builtin_amdgcn_mfma_f32_16x16x32_bf16(pf1, ones, lacc[1], 0, 0, 0);
  }
}

__global__ __launch_bounds__(256)
void attn2_kernel(const u16* __restrict__ QKV, const u16* __restrict__ Vt,
                  u16* __restrict__ ctx) {
  int tid = threadIdx.x, lane = tid & 63, w = tid >> 6;
  int g = lane >> 4, lr = lane & 15;
  int bh = blockIdx.y, b = bh >> 4, h = bh & 15;
  int q0[2];
  q0[0] = blockIdx.x * 64;
  q0[1] = (SEQ / 64 - 1 - blockIdx.x) * 64;
  const u16* Qh = QKV + (size_t)b * SEQ * QKVLD + (size_t)h * HDIM;
  const u16* Kh = Qh + 1024;
  const u16* Vth = Vt + (size_t)bh * HDIM * SEQ;

  bf16x8 ones;
#pragma unroll
  for (int j = 0; j < 8; ++j) ones[j] = (__bf16)1.0f;

  bf16x8 qf[2][2];
#pragma unroll
  for (int s = 0; s < 2; ++s)
#pragma unroll
    for (int kk = 0; kk < 2; ++kk)
      qf[s][kk] = *(const bf16x8*)(Qh + (size_t)(q0[s] + w * 16 + lr) * QKVLD + kk * 32 + g * 8);

  f32x4 lacc[2];
  f32x4 oacc[2][4];
#pragma unroll
  for (int s = 0; s < 2; ++s) {
    lacc[s][0] = 0.f; lacc[s][1] = 0.f; lacc[s][2] = 0.f; lacc[s][3] = 0.f;
#pragma unroll
    for (int nt = 0; nt < 4; ++nt) {
      oacc[s][nt][0] = 0.f; oacc[s][nt][1] = 0.f;
      oacc[s][nt][2] = 0.f; oacc[s][nt][3] = 0.f;
    }
  }

  int c1 = tid, c2 = tid + 256;
  int t1 = c1 >> 3, ch1 = (c1 ^ t1) & 7;
  int t2 = c2 >> 3, ch2 = (c2 ^ t2) & 7;
  for (int t0 = 0; t0 <= q0[1]; t0 += 64) {
    __syncthreads();
    gload16(Kh + (size_t)(t0 + t1) * QKVLD + ch1 * 8, attn_Kt + c1 * 8);
    gload16(Kh + (size_t)(t0 + t2) * QKVLD + ch2 * 8, attn_Kt + c2 * 8);
    gload16(Vth + (size_t)t1 * SEQ + t0 + ch1 * 8, attn_VT + c1 * 8);
    gload16(Vth + (size_t)t2 * SEQ + t0 + ch2 * 8, attn_VT + c2 * 8);
    __syncthreads();

    if (t0 <= q0[0])
      attn_tile<0>(t0, q0, w, g, lr, ones, qf, lacc, oacc);
    else
      attn_tile<1>(t0, q0, w, g, lr, ones, qf, lacc, oacc);
  }

#pragma unroll
  for (int s = 0; s < 2; ++s) {
    int srow = q0[s] + w * 16 + g * 4;
    float inv[4];
#pragma unroll
    for (int r = 0; r < 4; ++r) inv[r] = 1.0f / lacc[s][r];
#pragma unroll
    for (int nt = 0; nt < 4; ++nt) {
      int col = h * HDIM + nt * 16 + lr;
#pragma unroll
      for (int r = 0; r < 4; ++r) {
        float o = oacc[s][nt][r] * inv[r];
        ctx[((size_t)b * SEQ + srow + r) * EMB + col] = f2bf(o);
      }
    }
  }
}

// ---------------- launch ----------------
extern "C" void kernel_launch(void* const* d_in, const int* in_sizes, int n_in,
                              void* d_out, int out_size, void* d_ws, size_t ws_size,
                              hipStream_t stream) {
  const float* x    = (const float*)d_in[0];
  const float* Wq   = (const float*)d_in[2];
  const float* bq   = (const float*)d_in[3];
  const float* Wk   = (const float*)d_in[4];
  const float* bk   = (const float*)d_in[5];
  const float* Wv   = (const float*)d_in[6];
  const float* bv   = (const float*)d_in[7];
  const float* Wo   = (const float*)d_in[8];
  const float* bo   = (const float*)d_in[9];
  const float* W1   = (const float*)d_in[10];
  const float* b1   = (const float*)d_in[11];
  const float* W2   = (const float*)d_in[12];
  const float* b2   = (const float*)d_in[13];
  const float* ln1g = (const float*)d_in[14];
  const float* ln1b = (const float*)d_in[15];
  const float* ln2g = (const float*)d_in[16];
  const float* ln2b = (const float*)d_in[17];

  char* ws = (char*)d_ws;
  // layout (MB):
  //  0-6   WqkvT [3072,1024] bf16
  //  6-8   WoT
  //  8-16  W1T
  // 16-24  W2T
  // 24-32  xb (LN1 out bf16) -> x2b (LN2 out bf16)
  // 32-56  QKVb [4096,3072] bf16 (24MB)   -> 32-48 xpa fp32 / FFN2 partial z1
  // 56-64  ctxb [4096,1024] bf16          -> 48-64 x2f fp32 (after ctxb dead)
  // 64-72  VtG (8MB)                      -> 64-96 Wo partials -> h1 (32MB)
  u16* WqkvT = (u16*)(ws + ((size_t)0 << 20));
  u16* WoT   = (u16*)(ws + ((size_t)6 << 20));
  u16* W1T   = (u16*)(ws + ((size_t)8 << 20));
  u16* W2T   = (u16*)(ws + ((size_t)16 << 20));
  u16* xb    = (u16*)(ws + ((size_t)24 << 20));
  u16* QKVb  = (u16*)(ws + ((size_t)32 << 20));
  u16* ctxb  = (u16*)(ws + ((size_t)56 << 20));
  float* xpa = (float*)(ws + ((size_t)32 << 20));
  float* x2f = (float*)(ws + ((size_t)48 << 20));
  u16* x2b   = xb;
  u16* VtG   = (u16*)(ws + ((size_t)64 << 20));
  float* pWo = (float*)(ws + ((size_t)64 << 20));  // 2 x 16MB partials
  u16* h1    = (u16*)(ws + ((size_t)64 << 20));    // 32MB
  float* pF2 = (float*)(ws + ((size_t)0 << 20));   // z0 at 0-16; z1 at 32-48

  dim3 blk(256);
  const int M = NBATCH * SEQ; // 4096

  // weight transposes (fp32 -> bf16, [K,N] -> [N,K]); Wq/Wk/Wv fused into WqkvT
  wtrans_kernel<<<dim3(32, 32), blk, 0, stream>>>(Wq, WqkvT, EMB, EMB);
  wtrans_kernel<<<dim3(32, 32), blk, 0, stream>>>(Wk, WqkvT + (size_t)1024 * 1024, EMB, EMB);
  wtrans_kernel<<<dim3(32, 32), blk, 0, stream>>>(Wv, WqkvT + (size_t)2048 * 1024, EMB, EMB);
  wtrans_kernel<<<dim3(32, 32), blk, 0, stream>>>(Wo, WoT, EMB, EMB);
  wtrans_kernel<<<dim3(128, 32), blk, 0, stream>>>(W1, W1T, EMB, FFDIM);
  wtrans_kernel<<<dim3(32, 128), blk, 0, stream>>>(W2, W2T, FFDIM, EMB);

  // LN1
  ln_kernel<<<M / 4, blk, 0, stream>>>(x, ln1g, ln1b, xb, nullptr);

  // fused QKV projection (N=3072, grid 768; Q cols scaled by QSCALE)
  gemm_bt<<<dim3(QKVLD / 128, M / 128), blk, 0, stream>>>(
      xb, WqkvT, bq, bk, bv, QKVb, nullptr, M, QKVLD, EMB, 3, 1.0f, EMB, nullptr, 0);

  // V^T per head
  vtrans_kernel<<<dim3(SEQ / 64, NBATCH * NHEAD), blk, 0, stream>>>(QKVb, VtG);

  // attention (paired q-tiles: uniform 33 iterations/block)
  attn2_kernel<<<dim3(SEQ / 128, NBATCH * NHEAD), blk, 0, stream>>>(QKVb, VtG, ctxb);

  // output projection, split-K=2 -> partials at 64-96MB
  gemm_bt<<<dim3(EMB / 128, M / 128, 2), blk, 0, stream>>>(
      ctxb, WoT, nullptr, nullptr, nullptr, nullptr, nullptr, M, EMB, EMB, 4, 1.0f,
      EMB / 2, pWo, (size_t)4 << 20);
  // xpa = p0 + p1 + bo + x
  reduce2_kernel<<<M * EMB / 1024, blk, 0, stream>>>(pWo, (size_t)4 << 20, bo, x, xpa, EMB);

  // LN2 -> x2f fp32 + x2b bf16
  ln_kernel<<<M / 4, blk, 0, stream>>>(xpa, ln2g, ln2b, x2b, x2f);

  // FFN1 + exact GELU -> h1 bf16 (grid 1024)
  gemm_bt<<<dim3(FFDIM / 128, M / 128), blk, 0, stream>>>(
      x2b, W1T, b1, nullptr, nullptr, h1, nullptr, M, FFDIM, EMB, 1, 1.0f, EMB, nullptr, 0);

  // FFN2, split-K=2 -> partials z0 at 0-16MB, z1 at 32-48MB
  gemm_bt<<<dim3(EMB / 128, M / 128, 2), blk, 0, stream>>>(
      h1, W2T, nullptr, nullptr, nullptr, nullptr, nullptr, M, EMB, FFDIM, 4, 1.0f,
      FFDIM / 2, pF2, (size_t)8 << 20);
  // d_out = p0 + p1 + b2 + x2f
  reduce2_kernel<<<M * EMB / 1024, blk, 0, stream>>>(pF2, (size_t)8 << 20, b2, x2f,
                                                    (float*)d_out, EMB);
}

// Round 5
// 412.628 us; speedup vs baseline: 1.5514x; 1.1314x over previous
//
#include <hip/hip_runtime.h>
#include <cmath>

typedef unsigned short u16;
typedef unsigned int u32;
typedef __bf16 bf16x8 __attribute__((ext_vector_type(8)));
typedef float f32x4 __attribute__((ext_vector_type(4)));

#define SEQ 2048
#define EMB 1024
#define NHEAD 16
#define HDIM 64
#define FFDIM 4096
#define NBATCH 2
#define QKVLD 3072  // fused QKV row stride
#define PWS 68      // attn Pw row stride (u16)

// Q pre-scale folds 1/sqrt(64) and 1/ln(2) so softmax uses exp2 directly.
#define QSCALE 0.18033688011112042f

__device__ __forceinline__ u16 f2bf(float f) {
  u32 u = __float_as_uint(f);
  u32 r = u + 0x7fffu + ((u >> 16) & 1u);
  return (u16)(r >> 16);
}

__device__ __forceinline__ float ex2(float x) {
#if __has_builtin(__builtin_amdgcn_exp2f)
  return __builtin_amdgcn_exp2f(x);
#else
  return exp2f(x);
#endif
}

// tanh-form GELU via a single exp2: gelu(x) = x * sigmoid(2u),
// u = 0.7978845608*(x + 0.044715 x^3).  max |err| vs exact erf ~3e-3.
__device__ __forceinline__ float geluf(float x) {
  float u = 0.7978845608028654f * (x + 0.044715f * x * x * x);
  float e = ex2(2.8853900817779268f * u);  // exp(2u)
  return x - x / (e + 1.0f);
}

// async global->LDS, 16B per lane. LDS dest must be wave-uniform base + lane*16.
__device__ __forceinline__ void gload16(const void* g, void* l) {
  __builtin_amdgcn_global_load_lds(
      (const __attribute__((address_space(1))) unsigned int*)g,
      (__attribute__((address_space(3))) unsigned int*)l, 16, 0, 0);
}

// ---------------- weight transpose + fp32->bf16 ----------------
// W [K,N] fp32 -> WT [N,K] bf16 (generic, for W1/W2)
__global__ __launch_bounds__(256)
void wtrans_kernel(const float* __restrict__ W, u16* __restrict__ WT, int K, int N) {
  __shared__ float tile[32][33];
  int tx = threadIdx.x & 31, ty = threadIdx.x >> 5;
  int n0 = blockIdx.x * 32, k0 = blockIdx.y * 32;
#pragma unroll
  for (int i = 0; i < 32; i += 8)
    tile[ty + i][tx] = W[(size_t)(k0 + ty + i) * N + (n0 + tx)];
  __syncthreads();
#pragma unroll
  for (int i = 0; i < 32; i += 8)
    WT[(size_t)(n0 + ty + i) * K + (k0 + tx)] = f2bf(tile[tx][ty + i]);
}

// 4 square [1024x1024] weights in one dispatch: z=0..2 -> WqkvT rows, z=3 -> WoT
__global__ __launch_bounds__(256)
void wtrans4_kernel(const float* __restrict__ W0, const float* __restrict__ W1_,
                    const float* __restrict__ W2_, const float* __restrict__ W3,
                    u16* __restrict__ Dqkv, u16* __restrict__ Do) {
  __shared__ float tile[32][33];
  int z = blockIdx.z;
  const float* W = (z == 0) ? W0 : (z == 1) ? W1_ : (z == 2) ? W2_ : W3;
  u16* D = (z < 3) ? (Dqkv + (size_t)z * EMB * EMB) : Do;
  int tx = threadIdx.x & 31, ty = threadIdx.x >> 5;
  int n0 = blockIdx.x * 32, k0 = blockIdx.y * 32;
#pragma unroll
  for (int i = 0; i < 32; i += 8)
    tile[ty + i][tx] = W[(size_t)(k0 + ty + i) * EMB + (n0 + tx)];
  __syncthreads();
#pragma unroll
  for (int i = 0; i < 32; i += 8)
    D[(size_t)(n0 + ty + i) * EMB + (k0 + tx)] = f2bf(tile[tx][ty + i]);
}

// ---------------- V transpose per head: QKV [B*S,3072] (V at col 2048+h*64)
// -> Vt [B*H, 64, SEQ]
__global__ __launch_bounds__(256)
void vtrans_kernel(const u16* __restrict__ QKV, u16* __restrict__ Vt) {
  __shared__ u16 tile[64 * 72];
  int bh = blockIdx.y, b = bh >> 4, h = bh & 15;
  int s0 = blockIdx.x * 64;
  const u16* src = QKV + (size_t)b * SEQ * QKVLD + 2048 + (size_t)h * HDIM;
  int tid = threadIdx.x;
#pragma unroll
  for (int cc = 0; cc < 2; ++cc) {
    int c = tid + cc * 256;
    int s = c >> 3, d0 = (c & 7) * 8;
    uint4 v = *(const uint4*)(src + (size_t)(s0 + s) * QKVLD + d0);
    *(uint4*)(&tile[s * 72 + d0]) = v;
  }
  __syncthreads();
  u16* dst = Vt + (size_t)bh * HDIM * SEQ;
#pragma unroll
  for (int cc = 0; cc < 2; ++cc) {
    int c = tid + cc * 256;
    int d = c >> 3, t0l = (c & 7) * 8;
    union { uint4 u; u16 s[8]; } ou;
#pragma unroll
    for (int j = 0; j < 8; ++j) ou.s[j] = tile[(t0l + j) * 72 + d];
    *(uint4*)(dst + (size_t)d * SEQ + s0 + t0l) = ou.u;
  }
}

// ---------------- layernorm: 1 row per wave, 4 rows per block ----------------
__global__ __launch_bounds__(256)
void ln_kernel(const float* __restrict__ in, const float* __restrict__ gamma,
               const float* __restrict__ beta, u16* __restrict__ outb) {
  int w = threadIdx.x >> 6, lane = threadIdx.x & 63;
  int row = blockIdx.x * 4 + w;
  size_t base = (size_t)row * EMB;
  float4 v[4];
  float s = 0.f, q = 0.f;
#pragma unroll
  for (int j = 0; j < 4; ++j) {
    v[j] = *(const float4*)(in + base + j * 256 + lane * 4);
    s += v[j].x + v[j].y + v[j].z + v[j].w;
    q += v[j].x * v[j].x + v[j].y * v[j].y + v[j].z * v[j].z + v[j].w * v[j].w;
  }
#pragma unroll
  for (int off = 1; off < 64; off <<= 1) {
    s += __shfl_xor(s, off);
    q += __shfl_xor(q, off);
  }
  float mean = s * (1.0f / EMB);
  float var = q * (1.0f / EMB) - mean * mean;
  float rstd = rsqrtf(var + 1e-5f);
#pragma unroll
  for (int j = 0; j < 4; ++j) {
    int c = j * 256 + lane * 4;
    float4 g4 = *(const float4*)(gamma + c);
    float4 b4 = *(const float4*)(beta + c);
    ushort4 ob;
    ob.x = f2bf((v[j].x - mean) * rstd * g4.x + b4.x);
    ob.y = f2bf((v[j].y - mean) * rstd * g4.y + b4.y);
    ob.z = f2bf((v[j].z - mean) * rstd * g4.z + b4.z);
    ob.w = f2bf((v[j].w - mean) * rstd * g4.w + b4.w);
    *(ushort4*)(outb + base + c) = ob;
  }
}

// ---------------- LN2 fused with Wo split-K reduce ----------------
// in = p[0]+p[pstride]+bias(col)+resid; layernorm(in) -> bf16 + fp32
__global__ __launch_bounds__(256)
void ln2f_kernel(const float* __restrict__ p, size_t pstride,
                 const float* __restrict__ bias, const float* __restrict__ resid,
                 const float* __restrict__ gamma, const float* __restrict__ beta,
                 u16* __restrict__ outb, float* __restrict__ outf) {
  int w = threadIdx.x >> 6, lane = threadIdx.x & 63;
  int row = blockIdx.x * 4 + w;
  size_t base = (size_t)row * EMB;
  float4 v[4];
  float s = 0.f, q = 0.f;
#pragma unroll
  for (int j = 0; j < 4; ++j) {
    int c = j * 256 + lane * 4;
    float4 a = *(const float4*)(p + base + c);
    float4 b = *(const float4*)(p + pstride + base + c);
    float4 r = *(const float4*)(resid + base + c);
    float4 bb = *(const float4*)(bias + c);
    v[j].x = a.x + b.x + r.x + bb.x;
    v[j].y = a.y + b.y + r.y + bb.y;
    v[j].z = a.z + b.z + r.z + bb.z;
    v[j].w = a.w + b.w + r.w + bb.w;
    s += v[j].x + v[j].y + v[j].z + v[j].w;
    q += v[j].x * v[j].x + v[j].y * v[j].y + v[j].z * v[j].z + v[j].w * v[j].w;
  }
#pragma unroll
  for (int off = 1; off < 64; off <<= 1) {
    s += __shfl_xor(s, off);
    q += __shfl_xor(q, off);
  }
  float mean = s * (1.0f / EMB);
  float var = q * (1.0f / EMB) - mean * mean;
  float rstd = rsqrtf(var + 1e-5f);
#pragma unroll
  for (int j = 0; j < 4; ++j) {
    int c = j * 256 + lane * 4;
    float4 g4 = *(const float4*)(gamma + c);
    float4 b4 = *(const float4*)(beta + c);
    float y0 = (v[j].x - mean) * rstd * g4.x + b4.x;
    float y1 = (v[j].y - mean) * rstd * g4.y + b4.y;
    float y2 = (v[j].z - mean) * rstd * g4.z + b4.z;
    float y3 = (v[j].w - mean) * rstd * g4.w + b4.w;
    ushort4 ob;
    ob.x = f2bf(y0); ob.y = f2bf(y1); ob.z = f2bf(y2); ob.w = f2bf(y3);
    *(ushort4*)(outb + base + c) = ob;
    *(float4*)(outf + base + c) = make_float4(y0, y1, y2, y3);
  }
}

// ---------------- split-K reduce: out = p[z0]+p[z1]+bias+resid (fp32) --------
__global__ __launch_bounds__(256)
void reduce2_kernel(const float* __restrict__ p, size_t pstride,
                    const float* __restrict__ bias, const float* __restrict__ resid,
                    float* __restrict__ out, int ncols) {
  size_t i = ((size_t)blockIdx.x * 256 + threadIdx.x) * 4;
  float4 a = *(const float4*)(p + i);
  float4 b = *(const float4*)(p + pstride + i);
  float4 r = *(const float4*)(resid + i);
  int col = (int)(i & (size_t)(ncols - 1));
  float4 bb = *(const float4*)(bias + col);
  float4 o;
  o.x = a.x + b.x + r.x + bb.x;
  o.y = a.y + b.y + r.y + bb.y;
  o.z = a.z + b.z + r.z + bb.z;
  o.w = a.w + b.w + r.w + bb.w;
  *(float4*)(out + i) = o;
}

// ---------------- GEMM: C[M,N] = A[M,K](bf16) * BT[N,K]^T(bf16) --------------
// BK=64, XOR-swizzled LDS (slot s of row r holds global chunk s^(r&7)):
// frag ds_read_b128 spreads over all 32 banks at 2-way (free).
// mode 0: out bf16 = (acc+bias)*scale
// mode 1: out bf16 = gelu(acc+bias)
// mode 2: out fp32 = acc+bias+resid
// mode 3: out bf16 = (acc+bias{q,k,v})* (col<1024 ? QSCALE : 1)   [fused QKV]
// mode 4: partial[z*pstride + idx] = acc (raw fp32, split-K)
__global__ __launch_bounds__(256)
void gemm_bt(const u16* __restrict__ A, const u16* __restrict__ BT,
             const float* __restrict__ bias, const float* __restrict__ bias2,
             const float* __restrict__ bias3, void* __restrict__ out,
             const float* __restrict__ resid, int M, int N, int K,
             int mode, float scale, int ksplit,
             float* __restrict__ partial, size_t pstride) {
  __shared__ __align__(16) u16 As[128 * 64];
  __shared__ __align__(16) u16 Bs[128 * 64];
  int tid = threadIdx.x;
  int lane = tid & 63, w = tid >> 6;
  int wm = w >> 1, wn = w & 1;
  int g = lane >> 4, lr = lane & 15;
  int m0 = blockIdx.y * 128, n0 = blockIdx.x * 128;
  int z = blockIdx.z;
  int kbeg = z * ksplit, kend = kbeg + ksplit;

  f32x4 acc[4][4];
#pragma unroll
  for (int mt = 0; mt < 4; ++mt)
#pragma unroll
    for (int nt = 0; nt < 4; ++nt) {
      acc[mt][nt][0] = 0.f; acc[mt][nt][1] = 0.f;
      acc[mt][nt][2] = 0.f; acc[mt][nt][3] = 0.f;
    }

  // staging: 4 rounds per matrix; thread owns LDS bytes c*16 (row=c>>3, slot=c&7)
  size_t ao[4], bo_[4];
  int lo[4];
#pragma unroll
  for (int cc = 0; cc < 4; ++cc) {
    int c = tid + cc * 256;
    int row = c >> 3, slot = c & 7;
    int gc = slot ^ (row & 7);
    ao[cc] = (size_t)(m0 + row) * K + gc * 8;
    bo_[cc] = (size_t)(n0 + row) * K + gc * 8;
    lo[cc] = c * 8;
  }
  // frag LDS offsets
  int swz[2];
#pragma unroll
  for (int kk = 0; kk < 2; ++kk) swz[kk] = ((kk * 4 + g) ^ (lr & 7)) * 8;

  for (int k0 = kbeg; k0 < kend; k0 += 64) {
    __syncthreads();
#pragma unroll
    for (int cc = 0; cc < 4; ++cc) gload16(A + ao[cc] + k0, As + lo[cc]);
#pragma unroll
    for (int cc = 0; cc < 4; ++cc) gload16(BT + bo_[cc] + k0, Bs + lo[cc]);
    __syncthreads();  // vmcnt(0) drain before barrier -> LDS ready
#pragma unroll
    for (int kk = 0; kk < 2; ++kk) {
      bf16x8 af[4], bfr[4];
#pragma unroll
      for (int mt = 0; mt < 4; ++mt)
        af[mt] = *(const bf16x8*)(As + (wm * 64 + mt * 16 + lr) * 64 + swz[kk]);
#pragma unroll
      for (int nt = 0; nt < 4; ++nt)
        bfr[nt] = *(const bf16x8*)(Bs + (wn * 64 + nt * 16 + lr) * 64 + swz[kk]);
#pragma unroll
      for (int mt = 0; mt < 4; ++mt)
#pragma unroll
        for (int nt = 0; nt < 4; ++nt)
          acc[mt][nt] = __builtin_amdgcn_mfma_f32_16x16x32_bf16(af[mt], bfr[nt], acc[mt][nt], 0, 0, 0);
    }
  }

  float* pz = partial + (size_t)z * pstride;
#pragma unroll
  for (int mt = 0; mt < 4; ++mt) {
    int row = m0 + wm * 64 + mt * 16 + g * 4;
#pragma unroll
    for (int nt = 0; nt < 4; ++nt) {
      int col = n0 + wn * 64 + nt * 16 + lr;
      float bcol;
      if (mode == 3) {
        int which = col >> 10;
        const float* bp = (which == 0) ? bias : (which == 1) ? bias2 : bias3;
        bcol = bp[col & 1023];
      } else if (mode != 4) {
        bcol = bias[col];
      } else {
        bcol = 0.f;
      }
#pragma unroll
      for (int r = 0; r < 4; ++r) {
        float vacc = acc[mt][nt][r] + bcol;
        size_t idx = (size_t)(row + r) * N + col;
        if (mode == 0)      ((u16*)out)[idx] = f2bf(vacc * scale);
        else if (mode == 1) ((u16*)out)[idx] = f2bf(geluf(vacc));
        else if (mode == 2) ((float*)out)[idx] = vacc + resid[idx];
        else if (mode == 3) ((u16*)out)[idx] = f2bf(col < 1024 ? vacc * QSCALE : vacc);
        else                pz[idx] = vacc;
      }
    }
  }
}

// ---------------- flash attention, paired q-tiles, no-max exp2 softmax -------
__shared__ __align__(16) u16 attn_Kt[64 * 64];
__shared__ __align__(16) u16 attn_VT[64 * 64];
__shared__ __align__(16) u16 attn_Pw[2][4][16 * PWS];

template <int S0>
__device__ __forceinline__ void attn_tile(
    int t0, const int* q0, int w, int g, int lr, const bf16x8& ones,
    bf16x8 (&qf)[2][2], f32x4 (&lacc)[2], f32x4 (&oacc)[2][4]) {
  f32x4 sacc[2][4];
#pragma unroll
  for (int s = S0; s < 2; ++s)
#pragma unroll
    for (int nt = 0; nt < 4; ++nt) {
      sacc[s][nt][0] = 0.f; sacc[s][nt][1] = 0.f;
      sacc[s][nt][2] = 0.f; sacc[s][nt][3] = 0.f;
    }
#pragma unroll
  for (int kk = 0; kk < 2; ++kk)
#pragma unroll
    for (int nt = 0; nt < 4; ++nt) {
      int sw = ((kk * 4 + g) ^ lr) & 7;
      bf16x8 bfr = *(const bf16x8*)(&attn_Kt[(nt * 16 + lr) * 64 + sw * 8]);
      if (S0 == 0)
        sacc[0][nt] = __builtin_amdgcn_mfma_f32_16x16x32_bf16(qf[0][kk], bfr, sacc[0][nt], 0, 0, 0);
      sacc[1][nt] = __builtin_amdgcn_mfma_f32_16x16x32_bf16(qf[1][kk], bfr, sacc[1][nt], 0, 0, 0);
    }

#pragma unroll
  for (int s = S0; s < 2; ++s) {
    bool diag = (t0 == q0[s]);  // wave-uniform
#pragma unroll
    for (int r = 0; r < 4; ++r) {
#pragma unroll
      for (int nt = 0; nt < 4; ++nt) {
        float pv = ex2(sacc[s][nt][r]);
        if (diag && (nt * 16 + lr > w * 16 + g * 4 + r)) pv = 0.f;
        attn_Pw[s][w][(g * 4 + r) * PWS + nt * 16 + lr] = f2bf(pv);
      }
    }
  }

#pragma unroll
  for (int kk = 0; kk < 2; ++kk) {
    bf16x8 pf0, pf1;
    if (S0 == 0) pf0 = *(const bf16x8*)(&attn_Pw[0][w][lr * PWS + kk * 32 + g * 8]);
    pf1 = *(const bf16x8*)(&attn_Pw[1][w][lr * PWS + kk * 32 + g * 8]);
#pragma unroll
    for (int nt = 0; nt < 4; ++nt) {
      int sw = ((kk * 4 + g) ^ lr) & 7;
      bf16x8 vf = *(const bf16x8*)(&attn_VT[(nt * 16 + lr) * 64 + sw * 8]);
      if (S0 == 0)
        oacc[0][nt] = __builtin_amdgcn_mfma_f32_16x16x32_bf16(pf0, vf, oacc[0][nt], 0, 0, 0);
      oacc[1][nt] = __builtin_amdgcn_mfma_f32_16x16x32_bf16(pf1, vf, oacc[1][nt], 0, 0, 0);
    }
    if (S0 == 0)
      lacc[0] = __builtin_amdgcn_mfma_f32_16x16x32_bf16(pf0, ones, lacc[0], 0, 0, 0);
    lacc[1] = __builtin_amdgcn_mfma_f32_16x16x32_bf16(pf1, ones, lacc[1], 0, 0, 0);
  }
}

__global__ __launch_bounds__(256)
void attn2_kernel(const u16* __restrict__ QKV, const u16* __restrict__ Vt,
                  u16* __restrict__ ctx) {
  int tid = threadIdx.x, lane = tid & 63, w = tid >> 6;
  int g = lane >> 4, lr = lane & 15;
  int bh = blockIdx.y, b = bh >> 4, h = bh & 15;
  int q0[2];
  q0[0] = blockIdx.x * 64;
  q0[1] = (SEQ / 64 - 1 - blockIdx.x) * 64;
  const u16* Qh = QKV + (size_t)b * SEQ * QKVLD + (size_t)h * HDIM;
  const u16* Kh = Qh + 1024;
  const u16* Vth = Vt + (size_t)bh * HDIM * SEQ;

  bf16x8 ones;
#pragma unroll
  for (int j = 0; j < 8; ++j) ones[j] = (__bf16)1.0f;

  bf16x8 qf[2][2];
#pragma unroll
  for (int s = 0; s < 2; ++s)
#pragma unroll
    for (int kk = 0; kk < 2; ++kk)
      qf[s][kk] = *(const bf16x8*)(Qh + (size_t)(q0[s] + w * 16 + lr) * QKVLD + kk * 32 + g * 8);

  f32x4 lacc[2];
  f32x4 oacc[2][4];
#pragma unroll
  for (int s = 0; s < 2; ++s) {
    lacc[s][0] = 0.f; lacc[s][1] = 0.f; lacc[s][2] = 0.f; lacc[s][3] = 0.f;
#pragma unroll
    for (int nt = 0; nt < 4; ++nt) {
      oacc[s][nt][0] = 0.f; oacc[s][nt][1] = 0.f;
      oacc[s][nt][2] = 0.f; oacc[s][nt][3] = 0.f;
    }
  }

  int c1 = tid, c2 = tid + 256;
  int t1 = c1 >> 3, ch1 = (c1 ^ t1) & 7;
  int t2 = c2 >> 3, ch2 = (c2 ^ t2) & 7;
  for (int t0 = 0; t0 <= q0[1]; t0 += 64) {
    __syncthreads();
    gload16(Kh + (size_t)(t0 + t1) * QKVLD + ch1 * 8, attn_Kt + c1 * 8);
    gload16(Kh + (size_t)(t0 + t2) * QKVLD + ch2 * 8, attn_Kt + c2 * 8);
    gload16(Vth + (size_t)t1 * SEQ + t0 + ch1 * 8, attn_VT + c1 * 8);
    gload16(Vth + (size_t)t2 * SEQ + t0 + ch2 * 8, attn_VT + c2 * 8);
    __syncthreads();

    if (t0 <= q0[0])
      attn_tile<0>(t0, q0, w, g, lr, ones, qf, lacc, oacc);
    else
      attn_tile<1>(t0, q0, w, g, lr, ones, qf, lacc, oacc);
  }

#pragma unroll
  for (int s = 0; s < 2; ++s) {
    int srow = q0[s] + w * 16 + g * 4;
    float inv[4];
#pragma unroll
    for (int r = 0; r < 4; ++r) inv[r] = 1.0f / lacc[s][r];
#pragma unroll
    for (int nt = 0; nt < 4; ++nt) {
      int col = h * HDIM + nt * 16 + lr;
#pragma unroll
      for (int r = 0; r < 4; ++r) {
        float o = oacc[s][nt][r] * inv[r];
        ctx[((size_t)b * SEQ + srow + r) * EMB + col] = f2bf(o);
      }
    }
  }
}

// ---------------- launch ----------------
extern "C" void kernel_launch(void* const* d_in, const int* in_sizes, int n_in,
                              void* d_out, int out_size, void* d_ws, size_t ws_size,
                              hipStream_t stream) {
  const float* x    = (const float*)d_in[0];
  const float* Wq   = (const float*)d_in[2];
  const float* bq   = (const float*)d_in[3];
  const float* Wk   = (const float*)d_in[4];
  const float* bk   = (const float*)d_in[5];
  const float* Wv   = (const float*)d_in[6];
  const float* bv   = (const float*)d_in[7];
  const float* Wo   = (const float*)d_in[8];
  const float* bo   = (const float*)d_in[9];
  const float* W1   = (const float*)d_in[10];
  const float* b1   = (const float*)d_in[11];
  const float* W2   = (const float*)d_in[12];
  const float* b2   = (const float*)d_in[13];
  const float* ln1g = (const float*)d_in[14];
  const float* ln1b = (const float*)d_in[15];
  const float* ln2g = (const float*)d_in[16];
  const float* ln2b = (const float*)d_in[17];

  char* ws = (char*)d_ws;
  // layout (MB):
  //  0-6   WqkvT [3072,1024] bf16   -> FFN2 partial z0 (0-16, after W1T dead)
  //  6-8   WoT
  //  8-16  W1T
  // 16-24  W2T (live until FFN2 gemm done)
  // 24-32  xb (LN1 out bf16) -> x2b (LN2 out bf16)
  // 32-56  QKVb [4096,3072] bf16    -> 32-48 FFN2 partial z1 (after attn)
  // 48-64  x2f fp32 (after attn/Wo; QKVb upper + ctxb dead by then)
  // 56-64  ctxb [4096,1024] bf16 (live until Wo gemm)
  // 64-72  VtG (8MB)  -> 64-96 Wo partials (2x16MB) -> h1 (32MB)
  u16* WqkvT = (u16*)(ws + ((size_t)0 << 20));
  u16* WoT   = (u16*)(ws + ((size_t)6 << 20));
  u16* W1T   = (u16*)(ws + ((size_t)8 << 20));
  u16* W2T   = (u16*)(ws + ((size_t)16 << 20));
  u16* xb    = (u16*)(ws + ((size_t)24 << 20));
  u16* QKVb  = (u16*)(ws + ((size_t)32 << 20));
  u16* ctxb  = (u16*)(ws + ((size_t)56 << 20));
  float* x2f = (float*)(ws + ((size_t)48 << 20));
  u16* x2b   = xb;
  u16* VtG   = (u16*)(ws + ((size_t)64 << 20));
  float* pWo = (float*)(ws + ((size_t)64 << 20));  // 2 x 16MB partials
  u16* h1    = (u16*)(ws + ((size_t)64 << 20));    // 32MB
  float* pF2 = (float*)(ws + ((size_t)0 << 20));   // z0 at 0-16; z1 at 32-48

  dim3 blk(256);
  const int M = NBATCH * SEQ; // 4096

  // weight transposes (fp32 -> bf16, [K,N] -> [N,K])
  wtrans4_kernel<<<dim3(32, 32, 4), blk, 0, stream>>>(Wq, Wk, Wv, Wo, WqkvT, WoT);
  wtrans_kernel<<<dim3(128, 32), blk, 0, stream>>>(W1, W1T, EMB, FFDIM);
  wtrans_kernel<<<dim3(32, 128), blk, 0, stream>>>(W2, W2T, FFDIM, EMB);

  // LN1
  ln_kernel<<<M / 4, blk, 0, stream>>>(x, ln1g, ln1b, xb);

  // fused QKV projection (N=3072, grid 768; Q cols scaled by QSCALE)
  gemm_bt<<<dim3(QKVLD / 128, M / 128), blk, 0, stream>>>(
      xb, WqkvT, bq, bk, bv, QKVb, nullptr, M, QKVLD, EMB, 3, 1.0f, EMB, nullptr, 0);

  // V^T per head
  vtrans_kernel<<<dim3(SEQ / 64, NBATCH * NHEAD), blk, 0, stream>>>(QKVb, VtG);

  // attention (paired q-tiles: uniform 33 iterations/block)
  attn2_kernel<<<dim3(SEQ / 128, NBATCH * NHEAD), blk, 0, stream>>>(QKVb, VtG, ctxb);

  // output projection, split-K=2 -> partials at 64-96MB
  gemm_bt<<<dim3(EMB / 128, M / 128, 2), blk, 0, stream>>>(
      ctxb, WoT, nullptr, nullptr, nullptr, nullptr, nullptr, M, EMB, EMB, 4, 1.0f,
      EMB / 2, pWo, (size_t)4 << 20);

  // LN2 fused with Wo reduce (+bo+x residual) -> x2f fp32 + x2b bf16
  ln2f_kernel<<<M / 4, blk, 0, stream>>>(pWo, (size_t)4 << 20, bo, x, ln2g, ln2b,
                                         x2b, x2f);

  // FFN1 + fast GELU -> h1 bf16 (grid 1024)
  gemm_bt<<<dim3(FFDIM / 128, M / 128), blk, 0, stream>>>(
      x2b, W1T, b1, nullptr, nullptr, h1, nullptr, M, FFDIM, EMB, 1, 1.0f, EMB, nullptr, 0);

  // FFN2, split-K=2 -> partials z0 at 0-16MB, z1 at 32-48MB
  gemm_bt<<<dim3(EMB / 128, M / 128, 2), blk, 0, stream>>>(
      h1, W2T, nullptr, nullptr, nullptr, nullptr, nullptr, M, EMB, FFDIM, 4, 1.0f,
      FFDIM / 2, pF2, (size_t)8 << 20);
  // d_out = p0 + p1 + b2 + x2f
  reduce2_kernel<<<M * EMB / 1024, blk, 0, stream>>>(pF2, (size_t)8 << 20, b2, x2f,
                                                     (float*)d_out, EMB);
}